// Round 7
// baseline (297.753 us; speedup 1.0000x reference)
//
#include <hip/hip_runtime.h>

#define N_NODES 10000
#define E_EDGES 150000
#define KNB     15
#define EBLOCKS 587   // ceil(E/256)
#define GEMMB   626   // 313 rowBlks(32 rows) x 2 colBlks(128 cols)
#define KPAD    832   // 784 padded to 13*64
#define PLSTR   212992  // Bt plane stride = 256*832 (u16)
#define CFSTR   13312   // Bt 16-col step = 16*832 (u16)

typedef unsigned short u16;
typedef __bf16 bf16x8 __attribute__((ext_vector_type(8)));
typedef float  f32x4  __attribute__((ext_vector_type(4)));
typedef unsigned short u16x8 __attribute__((ext_vector_type(8)));

// ---------------------------------------------------------------------------
// Exact-ish bf16x3 split: a ~= hi + mid + lo. hi is RNE bf16 (Veltkamp step is
// exact in fp32), mid/lo truncated. Residual ~2^-25*|a|; dropped cross terms
// (mid*lo etc.) ~2^-26 => fp32-level accuracy with 6 MFMA terms (p+q<=2).
// ---------------------------------------------------------------------------
__device__ __forceinline__ void split3(float a, u16& h, u16& m, u16& l) {
    unsigned u = __float_as_uint(a);
    unsigned t = u + 0x7FFFu + ((u >> 16) & 1u);
    h = (u16)(t >> 16);
    float r1 = a - __uint_as_float(t & 0xFFFF0000u);
    unsigned u1 = __float_as_uint(r1);
    m = (u16)(u1 >> 16);
    float r2 = r1 - __uint_as_float(u1 & 0xFFFF0000u);
    l = (u16)(__float_as_uint(r2) >> 16);
}

// async global->LDS, 16B per lane; dst is wave-uniform base, HW adds lane*16.
__device__ __forceinline__ void gl_lds16(const u16* g, u16* l) {
    __builtin_amdgcn_global_load_lds(
        (const __attribute__((address_space(1))) unsigned int*)(g),
        (__attribute__((address_space(3))) unsigned int*)(l),
        16, 0, 0);
}

// ---------------------------------------------------------------------------
// CSR count: parallel global atomics — NEVER single-block this (R7 lesson).
// ---------------------------------------------------------------------------
__global__ void count_kernel(const int* __restrict__ idxs, int* __restrict__ cnt, int e) {
    int i = blockIdx.x * blockDim.x + threadIdx.x;
    if (i < e) atomicAdd(&cnt[idxs[i]], 1);
}

// ---------------------------------------------------------------------------
// gemm_tile2 (MR=2) — weight-space folds only
// ---------------------------------------------------------------------------
__device__ __forceinline__
void gemm_tile2(const float* __restrict__ A, int K,
                const float* __restrict__ Blo, const float* __restrict__ Bhi, int ldB,
                float* __restrict__ C, int ldC, int M,
                int rowBlk, int colBlk) {
    __shared__ float As2[16][34];
    __shared__ float Bs2[16][64];
    int tid = threadIdx.x;
    int tn  = tid & 15, tm = tid >> 4;
    int arow = tid >> 3, acB = (tid & 7) << 1;
    int brow = tid >> 4, bcol = (tid & 15) << 2;
    int rowBase = rowBlk * 32, colBase = colBlk * 64;

    bool half = (Bhi != nullptr) && (colBase >= 128);
    const float* B = half ? Bhi : Blo;
    int bj = colBase - (half ? 128 : 0) + bcol;

    float2 av; float4 bv;
    auto loadA = [&](int k0, float2& dst) {
        int gr = rowBase + arow;
        if (gr < M) dst = *(const float2*)(A + (size_t)gr * K + k0 + acB);
        else { dst.x = dst.y = 0.f; }
    };
    auto loadB = [&](int k0, float4& dst) {
        dst = *(const float4*)(B + (size_t)(k0 + brow) * ldB + bj);
    };
    loadA(0, av); loadB(0, bv);

    float acc[2][4] = {};
    for (int k0 = 0; k0 < K; k0 += 16) {
        __syncthreads();
        As2[acB + 0][arow] = av.x; As2[acB + 1][arow] = av.y;
        *(float4*)&Bs2[brow][bcol] = bv;
        __syncthreads();
        if (k0 + 16 < K) { loadA(k0 + 16, av); loadB(k0 + 16, bv); }
#pragma unroll
        for (int k = 0; k < 16; ++k) {
            float4 b = *(const float4*)&Bs2[k][tn << 2];
            float2 a = *(const float2*)&As2[k][tm << 1];
            acc[0][0] = fmaf(a.x, b.x, acc[0][0]); acc[0][1] = fmaf(a.x, b.y, acc[0][1]);
            acc[0][2] = fmaf(a.x, b.z, acc[0][2]); acc[0][3] = fmaf(a.x, b.w, acc[0][3]);
            acc[1][0] = fmaf(a.y, b.x, acc[1][0]); acc[1][1] = fmaf(a.y, b.y, acc[1][1]);
            acc[1][2] = fmaf(a.y, b.z, acc[1][2]); acc[1][3] = fmaf(a.y, b.w, acc[1][3]);
        }
    }
#pragma unroll
    for (int i = 0; i < 2; ++i) {
        int row = rowBase + tm * 2 + i;
        if (row >= M) continue;
#pragma unroll
        for (int j = 0; j < 4; ++j)
            C[(size_t)row * ldC + colBase + (tn << 2) + j] = acc[i][j];
    }
}

// ---------------------------------------------------------------------------
// scanfold: block 0 = prefix-scan of cnt; blocks 1..40 = weight folds;
// blocks 41..56 = bf16x3 split + transpose of [mw1|nw1] (rows 0..783, zero-pad
// to 832) into Bt[3][256][832] (bf16 bits, Bt[p][col][k] = B[k][col]).
// ---------------------------------------------------------------------------
__global__ __launch_bounds__(256)
void scanfold_kernel(const float* __restrict__ mw2, const float* __restrict__ mb2,
                     const float* __restrict__ nw1, const float* __restrict__ nb2,
                     const float* __restrict__ nw2,
                     const float* __restrict__ m2w1, const float* __restrict__ m2b1,
                     const float* __restrict__ m2w2, const float* __restrict__ m2b2,
                     const float* __restrict__ n2w1, const float* __restrict__ n2b1,
                     float* __restrict__ M1, float* __restrict__ M2,
                     float* __restrict__ WH,
                     float* __restrict__ v1, float* __restrict__ v2,
                     float* __restrict__ bu2, float* __restrict__ bx2,
                     const int* __restrict__ cnt, int* __restrict__ eoff,
                     float* __restrict__ maskv, int* __restrict__ fillc,
                     const float* __restrict__ mw1, u16* __restrict__ Bt) {
    int b = blockIdx.x;
    if (b >= 41) {
        // ---- bsplit: 16 cols per block, LDS transpose then split3 ----
        __shared__ float Lt[KPAD][17];
        int b2 = b - 41;
        int colBase = b2 * 16;
        const float* S = (colBase < 128) ? mw1 : nw1;
        int sc = colBase & 127;
        int tid = threadIdx.x;
        for (int i = 0; i < 52; ++i) {
            int row = (tid >> 4) + i * 16;
            Lt[row][tid & 15] = (row < 784) ? S[(size_t)row * 128 + sc + (tid & 15)] : 0.f;
        }
        __syncthreads();
        int col = tid >> 4, o = tid & 15;
        size_t dbase = (size_t)(colBase + col) * KPAD;
        for (int o2 = o; o2 < 104; o2 += 16) {
            u16 hs[8], ms[8], ls[8];
#pragma unroll
            for (int e = 0; e < 8; ++e) split3(Lt[o2 * 8 + e][col], hs[e], ms[e], ls[e]);
            auto pk = [](const u16* s) {
                uint4 v;
                v.x = s[0] | ((unsigned)s[1] << 16); v.y = s[2] | ((unsigned)s[3] << 16);
                v.z = s[4] | ((unsigned)s[5] << 16); v.w = s[6] | ((unsigned)s[7] << 16);
                return v;
            };
            *(uint4*)(Bt +           dbase + o2 * 8) = pk(hs);
            *(uint4*)(Bt + PLSTR   + dbase + o2 * 8) = pk(ms);
            *(uint4*)(Bt + 2*PLSTR + dbase + o2 * 8) = pk(ls);
        }
        return;
    }
    if (b == 0) {
        __shared__ int ssum[256];
        int tid = threadIdx.x;
        const int CH = 40;
        int base = tid * CH;
        int v[CH]; int s = 0;
#pragma unroll
        for (int q = 0; q < CH; ++q) {
            int i = base + q;
            v[q] = (i < N_NODES) ? cnt[i] : 0;
            s += v[q];
        }
        ssum[tid] = s;
        __syncthreads();
        for (int off = 1; off < 256; off <<= 1) {
            int t = (tid >= off) ? ssum[tid - off] : 0;
            __syncthreads();
            ssum[tid] += t;
            __syncthreads();
        }
        int ex = ssum[tid] - s;
#pragma unroll
        for (int q = 0; q < CH; ++q) {
            int i = base + q;
            if (i < N_NODES) {
                eoff[i]  = ex;
                maskv[i] = (v[q] > 0) ? 1.f : 0.f;
                fillc[i] = 0;
                ex += v[q];
            }
        }
        return;
    }
    b -= 1;
    if (b < 8) {
        gemm_tile2(mw2, 784, nw1 + 784 * 128, nullptr, 128, M1, 128, 128, b >> 1, b & 1);
    } else if (b < 16) {
        int t = b - 8;
        gemm_tile2(m2w2, 128, n2w1 + 128 * 128, nullptr, 128, M2, 128, 128, t >> 1, t & 1);
    } else if (b < 32) {
        int t = b - 16;
        gemm_tile2(nw2, 128, m2w1, n2w1, 128, WH, 256, 128, t >> 2, t & 3);
    } else {
        __shared__ float red[256];
        int t  = (b - 32) >> 1;
        int j  = ((b - 32) & 1) * 64 + (threadIdx.x & 63);
        int kq = threadIdx.x >> 6;
        const float* bvec; const float* Bv; const float* add; float* out; int Kv;
        if (t == 0)      { bvec = mb2;  Bv = nw1 + 784 * 128;  add = nullptr; out = v1;  Kv = 784; }
        else if (t == 1) { bvec = m2b2; Bv = n2w1 + 128 * 128; add = nullptr; out = v2;  Kv = 128; }
        else if (t == 2) { bvec = nb2;  Bv = m2w1;             add = m2b1;    out = bu2; Kv = 128; }
        else             { bvec = nb2;  Bv = n2w1;             add = n2b1;    out = bx2; Kv = 128; }
        float acc = 0.f;
        for (int k = kq; k < Kv; k += 4) acc = fmaf(bvec[k], Bv[k * 128 + j], acc);
        red[threadIdx.x] = acc;
        __syncthreads();
        if (threadIdx.x < 64) {
            float tot = red[threadIdx.x] + red[threadIdx.x + 64] +
                        red[threadIdx.x + 128] + red[threadIdx.x + 192];
            out[j] = tot + (add ? add[j] : 0.f);
        }
    }
}

// ---------------------------------------------------------------------------
// MFMA bf16x3 GEMM tile: 32 rows x 128 cols, BK=64.
// R6: B staged via __builtin_amdgcn_global_load_lds into ping-pong LDS
// (zero VGPR footprint -> the allocator CANNOT sink it; R1/R3/R5 all proved
// hipcc defeats register-resident B prefetch). Bt's fragment-linear layout is
// exactly the wave-uniform-base + lane*16 write pattern the instruction does;
// per-lane GLOBAL source is allowed. The compiler's vmcnt(0) drain before
// barrier #1 is the synchronization that makes B(t) resident (m97 pattern).
// A loads issued BEFORE B prefetch so A's wait is a counted vmcnt, not drain.
// LDS: Bsh 96KB + As 12KB = 108KB -> 1 block/CU.
// ---------------------------------------------------------------------------
#define MF(a, b, c) __builtin_amdgcn_mfma_f32_16x16x32_bf16((a), (b), (c), 0, 0, 0)

__device__ __forceinline__
void gemm_mfma(const float* __restrict__ A, const u16* __restrict__ Bt,
               const float* __restrict__ biasLo, const float* __restrict__ biasHi,
               const float* __restrict__ vhi, const float* __restrict__ rowmask,
               float* __restrict__ C, int gb) {
    __shared__ u16 As[3][2][2][64][8];    // 12 KB [plane][kt][rowfrag][lane][e]
    __shared__ u16 Bsh[2][4][12][64][8];  // 96 KB [buf][wave][chunk][lane][e]
    const int tid  = threadIdx.x;
    const int lane = tid & 63, w = tid >> 6;
    const int rb = gb >> 1, cb = gb & 1;
    const int rowBase = rb * 32, colBase = cb * 128;
    u16* const AsB = &As[0][0][0][0][0];

    // ---- A staging: wave w -> (kt=w>>1, rf=w&1); lane l -> row rf*16+(l&15),
    //      k-octet l>>4 within the kt-half ----
    const int skt = w >> 1, srf = w & 1;
    const int aoff = skt * 32 + ((lane >> 4) << 3);     // k offset in 64-tile
    int arow = rowBase + srf * 16 + (lane & 15);
    if (arow > N_NODES - 1) arow = N_NODES - 1;
    const float* Ap = A + (size_t)arow * 784;
    u16* aDst = AsB + skt * 1024 + srf * 512 + (lane << 3);   // +2048/plane

    // ---- B per-lane global base: this wave's cols, this lane's (col, k-oct) --
    const u16* Bp = Bt + (size_t)(colBase + w * 32 + (lane & 15)) * KPAD
                       + ((lane >> 4) << 3);
    // chunk c = pl*4 + kt*2 + cf: src += pl*PLSTR + cf*CFSTR + kt*32 (+k0)
    //                             dst  = waveBase + c*512 (u16), HW adds lane*8

    float4 av0, av1;
    u16x8 a3h, a3m, a3l;

#define ALOAD(k0) { int kk = (k0) + aoff; \
    if (kk < 784) { av0 = *(const float4*)(Ap + kk); av1 = *(const float4*)(Ap + kk + 4); } \
    else { av0.x=av0.y=av0.z=av0.w=0.f; av1 = av0; } }
#define ASPLIT() { u16 h, m, l; \
    split3(av0.x, h, m, l); a3h[0] = h; a3m[0] = m; a3l[0] = l; \
    split3(av0.y, h, m, l); a3h[1] = h; a3m[1] = m; a3l[1] = l; \
    split3(av0.z, h, m, l); a3h[2] = h; a3m[2] = m; a3l[2] = l; \
    split3(av0.w, h, m, l); a3h[3] = h; a3m[3] = m; a3l[3] = l; \
    split3(av1.x, h, m, l); a3h[4] = h; a3m[4] = m; a3l[4] = l; \
    split3(av1.y, h, m, l); a3h[5] = h; a3m[5] = m; a3l[5] = l; \
    split3(av1.z, h, m, l); a3h[6] = h; a3m[6] = m; a3l[6] = l; \
    split3(av1.w, h, m, l); a3h[7] = h; a3m[7] = m; a3l[7] = l; }
#define BPREF(D, k0) { \
    u16* d_ = (D); \
    const u16* s_ = Bp + (k0); \
    gl_lds16(s_,                        d_); \
    gl_lds16(s_ + CFSTR,                d_ + 512); \
    gl_lds16(s_ + 32,                   d_ + 1024); \
    gl_lds16(s_ + CFSTR + 32,           d_ + 1536); \
    gl_lds16(s_ + PLSTR,                d_ + 2048); \
    gl_lds16(s_ + PLSTR + CFSTR,        d_ + 2560); \
    gl_lds16(s_ + PLSTR + 32,           d_ + 3072); \
    gl_lds16(s_ + PLSTR + CFSTR + 32,   d_ + 3584); \
    gl_lds16(s_ + 2*PLSTR,              d_ + 4096); \
    gl_lds16(s_ + 2*PLSTR + CFSTR,      d_ + 4608); \
    gl_lds16(s_ + 2*PLSTR + 32,         d_ + 5120); \
    gl_lds16(s_ + 2*PLSTR + CFSTR + 32, d_ + 5632); }

    f32x4 acc00 = {0.f, 0.f, 0.f, 0.f};
    f32x4 acc01 = acc00, acc10 = acc00, acc11 = acc00;

    const u16* aFr = AsB + (lane << 3);   // +512/rf, +1024/kt, +2048/plane

    ALOAD(0) ASPLIT()
    BPREF(&Bsh[0][w][0][0][0], 0)

    for (int t = 0; t < 13; ++t) {
        __syncthreads();                      // drains vmcnt: B(t) in LDS
        *(u16x8*)(aDst)        = a3h;
        *(u16x8*)(aDst + 2048) = a3m;
        *(u16x8*)(aDst + 4096) = a3l;
        __syncthreads();                      // As(t) visible
        if (t < 12) {
            ALOAD((t + 1) << 6)               // A first (counted wait later)
            BPREF(&Bsh[(t + 1) & 1][w][0][0][0], (t + 1) << 6)
        }
        const u16* dB = &Bsh[t & 1][w][0][0][0] + (lane << 3);
        // ---- KT = 0 ----
        {
            bf16x8 a0h = *(const bf16x8*)(aFr);
            bf16x8 a1h = *(const bf16x8*)(aFr + 512);
            bf16x8 a0m = *(const bf16x8*)(aFr + 2048);
            bf16x8 a1m = *(const bf16x8*)(aFr + 2560);
            bf16x8 a0l = *(const bf16x8*)(aFr + 4096);
            bf16x8 a1l = *(const bf16x8*)(aFr + 4608);
            bf16x8 bh00 = *(const bf16x8*)(dB);
            bf16x8 bh01 = *(const bf16x8*)(dB + 512);
            bf16x8 bm00 = *(const bf16x8*)(dB + 2048);
            bf16x8 bm01 = *(const bf16x8*)(dB + 2560);
            bf16x8 bl00 = *(const bf16x8*)(dB + 4096);
            bf16x8 bl01 = *(const bf16x8*)(dB + 4608);
            acc00 = MF(a0h, bh00, acc00); acc01 = MF(a0h, bh01, acc01);
            acc10 = MF(a1h, bh00, acc10); acc11 = MF(a1h, bh01, acc11);
            acc00 = MF(a0m, bh00, acc00); acc01 = MF(a0m, bh01, acc01);
            acc10 = MF(a1m, bh00, acc10); acc11 = MF(a1m, bh01, acc11);
            acc00 = MF(a0l, bh00, acc00); acc01 = MF(a0l, bh01, acc01);
            acc10 = MF(a1l, bh00, acc10); acc11 = MF(a1l, bh01, acc11);
            acc00 = MF(a0h, bm00, acc00); acc01 = MF(a0h, bm01, acc01);
            acc10 = MF(a1h, bm00, acc10); acc11 = MF(a1h, bm01, acc11);
            acc00 = MF(a0m, bm00, acc00); acc01 = MF(a0m, bm01, acc01);
            acc10 = MF(a1m, bm00, acc10); acc11 = MF(a1m, bm01, acc11);
            acc00 = MF(a0h, bl00, acc00); acc01 = MF(a0h, bl01, acc01);
            acc10 = MF(a1h, bl00, acc10); acc11 = MF(a1h, bl01, acc11);
        }
        // ---- KT = 1 ----
        {
            bf16x8 a0h = *(const bf16x8*)(aFr + 1024);
            bf16x8 a1h = *(const bf16x8*)(aFr + 1536);
            bf16x8 a0m = *(const bf16x8*)(aFr + 3072);
            bf16x8 a1m = *(const bf16x8*)(aFr + 3584);
            bf16x8 a0l = *(const bf16x8*)(aFr + 5120);
            bf16x8 a1l = *(const bf16x8*)(aFr + 5632);
            bf16x8 bh10 = *(const bf16x8*)(dB + 1024);
            bf16x8 bh11 = *(const bf16x8*)(dB + 1536);
            bf16x8 bm10 = *(const bf16x8*)(dB + 3072);
            bf16x8 bm11 = *(const bf16x8*)(dB + 3584);
            bf16x8 bl10 = *(const bf16x8*)(dB + 5120);
            bf16x8 bl11 = *(const bf16x8*)(dB + 5632);
            acc00 = MF(a0h, bh10, acc00); acc01 = MF(a0h, bh11, acc01);
            acc10 = MF(a1h, bh10, acc10); acc11 = MF(a1h, bh11, acc11);
            acc00 = MF(a0m, bh10, acc00); acc01 = MF(a0m, bh11, acc01);
            acc10 = MF(a1m, bh10, acc10); acc11 = MF(a1m, bh11, acc11);
            acc00 = MF(a0l, bh10, acc00); acc01 = MF(a0l, bh11, acc01);
            acc10 = MF(a1l, bh10, acc10); acc11 = MF(a1l, bh11, acc11);
            acc00 = MF(a0h, bm10, acc00); acc01 = MF(a0h, bm11, acc01);
            acc10 = MF(a1h, bm10, acc10); acc11 = MF(a1h, bm11, acc11);
            acc00 = MF(a0m, bm10, acc00); acc01 = MF(a0m, bm11, acc01);
            acc10 = MF(a1m, bm10, acc10); acc11 = MF(a1m, bm11, acc11);
            acc00 = MF(a0h, bl10, acc00); acc01 = MF(a0h, bl11, acc01);
            acc10 = MF(a1h, bl10, acc10); acc11 = MF(a1h, bl11, acc11);
        }
        if (t < 12) ASPLIT()
    }
#undef ALOAD
#undef ASPLIT
#undef BPREF

    // epilogue: C row = (lane>>4)*4+r, col = lane&15 within each 16x16 frag
    const float* bias = cb ? biasHi : biasLo;
#define EPI(rf, cf, ACC) { \
        const int col = colBase + w * 32 + (cf) * 16 + (lane & 15); \
        const int cj  = col & 127; \
        const float bb = bias[cj]; \
        const float vh = cb ? vhi[cj] : 0.f; \
        const int rbase = rowBase + (rf) * 16 + ((lane >> 4) << 2); \
        _Pragma("unroll") \
        for (int rr = 0; rr < 4; ++rr) { \
            int row = rbase + rr; \
            if (row < N_NODES) { \
                float v = ACC[rr] + bb; \
                if (cb) v = fmaf(rowmask[row], vh, v); \
                C[(size_t)row * 256 + col] = v; \
            } } }
    EPI(0, 0, acc00) EPI(0, 1, acc01) EPI(1, 0, acc10) EPI(1, 1, acc11)
#undef EPI
}

// ---------------------------------------------------------------------------
// fillgemm: blocks [0,GEMMB) = MFMA GEMM (long blocks first, LPT);
//           blocks [GEMMB, GEMMB+EBLOCKS) = CSR fill.
// ---------------------------------------------------------------------------
__global__ __launch_bounds__(256, 1)
void fillgemm_kernel(const int* __restrict__ idxs, const float* __restrict__ ea,
                     const int* __restrict__ eoff, int* __restrict__ fillc,
                     float* __restrict__ eas,
                     const float* __restrict__ A, const u16* __restrict__ Bt,
                     const float* __restrict__ biasLo, const float* __restrict__ biasHi,
                     const float* __restrict__ vhi, const float* __restrict__ rowmask,
                     float* __restrict__ C) {
    int gb = blockIdx.x;
    if (gb < GEMMB) {
        gemm_mfma(A, Bt, biasLo, biasHi, vhi, rowmask, C, gb);
        return;
    }
    int i = (gb - GEMMB) * 256 + threadIdx.x;
    if (i < E_EDGES) {
        int s = idxs[i];
        int p = atomicAdd(&fillc[s], 1);
        eas[eoff[s] + p] = ea[i];
    }
}

// ---------------------------------------------------------------------------
// tail16 @ 512 threads (R2 lesson: tail is per-block-latency-bound — all 625
// blocks co-resident, so duration == one block's serial chain).
// ---------------------------------------------------------------------------
__global__ __launch_bounds__(512, 4)
void tail16_kernel(const float* __restrict__ UX1, const float* __restrict__ w1last,
                   const float* __restrict__ eas, const int* __restrict__ eoff,
                   const int* __restrict__ cnt, const float* __restrict__ maskv,
                   const float* __restrict__ M1, const float* __restrict__ WH,
                   const float* __restrict__ bu2, const float* __restrict__ bx2,
                   const float* __restrict__ v2,
                   const float* __restrict__ w2last, const float* __restrict__ M2,
                   const float* __restrict__ pw, const float* __restrict__ pb,
                   float* __restrict__ UX2, float* __restrict__ proj) {
    __shared__ float Bs[16][264];    // B staging (all GEMM phases)
    __shared__ float mhT[128][18];   // msg means [k][m]
    __shared__ float ts[16][132];    // z1 rows
    __shared__ float ebuf[1024];     // CSR edge window
    int rowBase = blockIdx.x * 16;   // 625*16 = 10000 exact
    int tid = threadIdx.x;
    int tr  = tid >> 5;              // 0..15 — this thread's GEMM row
    int tn  = tid & 31;
    int c4  = tn << 2;

    auto msg_phase = [&](const float* __restrict__ U, const float* __restrict__ wl) {
        int d = tid & 127, grp = tid >> 7;   // grp 0..3, wave-uniform
        float w = wl[d];
        float uu[4], sum[4];
        int es[4], ec[4];
#pragma unroll
        for (int it = 0; it < 4; ++it) {
            int n  = rowBase + it * 4 + grp;
            ec[it] = cnt[n];
            es[it] = eoff[n];
            uu[it] = U[(size_t)n * 256 + d];
            sum[it] = 0.f;
        }
        int ebase = eoff[rowBase];
        int eend  = (rowBase + 16 < N_NODES) ? eoff[rowBase + 16] : E_EDGES;
        for (int w0 = ebase; w0 < eend; w0 += 1024) {
            int wlen = min(1024, eend - w0);
            __syncthreads();
            for (int q = tid; q < wlen; q += 512) ebuf[q] = eas[w0 + q];
            __syncthreads();
#pragma unroll
            for (int it = 0; it < 4; ++it) {
                int lo = max(es[it], w0), hiE = min(es[it] + ec[it], w0 + wlen);
                for (int e = lo; e < hiE; ++e)
                    sum[it] += fmaxf(fmaf(ebuf[e - w0], w, uu[it]), 0.f);
            }
        }
#pragma unroll
        for (int it = 0; it < 4; ++it)
            mhT[d][it * 4 + grp] = (ec[it] > 0) ? sum[it] / (float)ec[it] : 0.f;
    };

    // ===== msg1 =====
    msg_phase(UX1, w1last);

    // ===== phase1: ts = relu(xn1 + mhT @ M1), 16x128, 1 row/thread =====
    {
        float a0 = 0.f, a1 = 0.f, a2 = 0.f, a3 = 0.f;
        float4 bv = *(const float4*)(M1 + (size_t)tr * 128 + c4);
        for (int k0 = 0; k0 < 128; k0 += 16) {
            __syncthreads();                 // Bs free + (k0=0) mhT ready
            *(float4*)&Bs[tr][c4] = bv;
            __syncthreads();
            if (k0 + 16 < 128)
                bv = *(const float4*)(M1 + (size_t)(k0 + 16 + tr) * 128 + c4);
#pragma unroll
            for (int k = 0; k < 16; ++k) {
                float a = mhT[k0 + k][tr];
                float4 b = *(const float4*)&Bs[k][c4];
                a0 = fmaf(a, b.x, a0); a1 = fmaf(a, b.y, a1);
                a2 = fmaf(a, b.z, a2); a3 = fmaf(a, b.w, a3);
            }
        }
        int row = rowBase + tr;
        float4 xn = *(const float4*)(UX1 + (size_t)row * 256 + 128 + c4);
        float4 o;
        o.x = fmaxf(a0 + xn.x, 0.f);
        o.y = fmaxf(a1 + xn.y, 0.f);
        o.z = fmaxf(a2 + xn.z, 0.f);
        o.w = fmaxf(a3 + xn.w, 0.f);
        *(float4*)&ts[tr][c4] = o;
    }

    // ===== phase2: UX2 = ts @ WH + bias (+maskv*v2 on hi), 16x256 =====
    {
        float u0 = 0.f, u1 = 0.f, u2 = 0.f, u3 = 0.f;
        float x0 = 0.f, x1 = 0.f, x2 = 0.f, x3 = 0.f;
        int c8 = tn << 3;
        float4 bva = *(const float4*)(WH + (size_t)tr * 256 + c8);
        float4 bvb = *(const float4*)(WH + (size_t)tr * 256 + c8 + 4);
        for (int k0 = 0; k0 < 128; k0 += 16) {
            __syncthreads();                 // orders ts writes / Bs reuse
            *(float4*)&Bs[tr][c8]     = bva;
            *(float4*)&Bs[tr][c8 + 4] = bvb;
            __syncthreads();
            if (k0 + 16 < 128) {
                bva = *(const float4*)(WH + (size_t)(k0 + 16 + tr) * 256 + c8);
                bvb = *(const float4*)(WH + (size_t)(k0 + 16 + tr) * 256 + c8 + 4);
            }
#pragma unroll
            for (int k = 0; k < 16; ++k) {
                float a = ts[tr][k0 + k];
                float4 b0 = *(const float4*)&Bs[k][c4];          // cols 4tn..   (u half)
                float4 b1 = *(const float4*)&Bs[k][c4 + 128];    // cols 128+4tn (x half)
                u0 = fmaf(a, b0.x, u0); u1 = fmaf(a, b0.y, u1);
                u2 = fmaf(a, b0.z, u2); u3 = fmaf(a, b0.w, u3);
                x0 = fmaf(a, b1.x, x0); x1 = fmaf(a, b1.y, x1);
                x2 = fmaf(a, b1.z, x2); x3 = fmaf(a, b1.w, x3);
            }
        }
        int row = rowBase + tr;
        float rm = maskv[row];
        float4 o0, o1;
        o0.x = u0 + bu2[c4 + 0]; o0.y = u1 + bu2[c4 + 1];
        o0.z = u2 + bu2[c4 + 2]; o0.w = u3 + bu2[c4 + 3];
        o1.x = fmaf(rm, v2[c4 + 0], x0 + bx2[c4 + 0]);
        o1.y = fmaf(rm, v2[c4 + 1], x1 + bx2[c4 + 1]);
        o1.z = fmaf(rm, v2[c4 + 2], x2 + bx2[c4 + 2]);
        o1.w = fmaf(rm, v2[c4 + 3], x3 + bx2[c4 + 3]);
        float* orow = UX2 + (size_t)row * 256;
        *(float4*)(orow + c4)       = o0;
        *(float4*)(orow + 128 + c4) = o1;
    }
    __syncthreads();   // UX2 block-visible (own rows only are read below)

    // ===== msg2 =====
    msg_phase(UX2, w2last);

    // ===== phase4: z2 = relu(xn2 + mhT@M2); proj = z2@pw + pb =====
    {
        float a0 = 0.f, a1 = 0.f, a2 = 0.f, a3 = 0.f;
        float4 bv = *(const float4*)(M2 + (size_t)tr * 128 + c4);
        for (int k0 = 0; k0 < 128; k0 += 16) {
            __syncthreads();                 // orders msg2's mhT writes
            *(float4*)&Bs[tr][c4] = bv;
            __syncthreads();
            if (k0 + 16 < 128)
                bv = *(const float4*)(M2 + (size_t)(k0 + 16 + tr) * 128 + c4);
#pragma unroll
            for (int k = 0; k < 16; ++k) {
                float a = mhT[k0 + k][tr];
                float4 b = *(const float4*)&Bs[k][c4];
                a0 = fmaf(a, b.x, a0); a1 = fmaf(a, b.y, a1);
                a2 = fmaf(a, b.z, a2); a3 = fmaf(a, b.w, a3);
            }
        }
        int row = rowBase + tr;
        float4 xn = *(const float4*)(UX2 + (size_t)row * 256 + 128 + c4);
        float t0 = fmaxf(a0 + xn.x, 0.f);
        float t1 = fmaxf(a1 + xn.y, 0.f);
        float t2 = fmaxf(a2 + xn.z, 0.f);
        float t3 = fmaxf(a3 + xn.w, 0.f);
        float pp0 = fmaf(t3, pw[2*(c4+3)],   fmaf(t2, pw[2*(c4+2)],   fmaf(t1, pw[2*(c4+1)],   t0 * pw[2*c4])));
        float pp1 = fmaf(t3, pw[2*(c4+3)+1], fmaf(t2, pw[2*(c4+2)+1], fmaf(t1, pw[2*(c4+1)+1], t0 * pw[2*c4+1])));
        for (int off = 16; off > 0; off >>= 1) {
            pp0 += __shfl_xor(pp0, off, 64);
            pp1 += __shfl_xor(pp1, off, 64);
        }
        if (tn == 0) {
            proj[2 * row]     = pp0 + pb[0];
            proj[2 * row + 1] = pp1 + pb[1];
        }
    }
}

__global__ void dist_kernel(const float* __restrict__ proj, const int* __restrict__ idxs,
                            float* __restrict__ out, int e) {
    int i = blockIdx.x * blockDim.x + threadIdx.x;
    if (i >= e) return;
    int n = i / KNB;
    int m = idxs[i];
    float2 pn = *(const float2*)(proj + 2 * n);
    float2 pm = *(const float2*)(proj + 2 * m);
    float dx = pn.x - pm.x;
    float dy = pn.y - pm.y;
    out[i] = dx * dx + dy * dy;
}

// ---------------------------------------------------------------------------
extern "C" void kernel_launch(void* const* d_in, const int* in_sizes, int n_in,
                              void* d_out, int out_size, void* d_ws, size_t ws_size,
                              hipStream_t stream) {
    (void)in_sizes; (void)n_in; (void)out_size; (void)ws_size;
    const float* x    = (const float*)d_in[0];
    const float* eatt = (const float*)d_in[1];
    const int*   idxs = (const int*)d_in[2];
    const float* mw1  = (const float*)d_in[3];
    const float* mb1  = (const float*)d_in[4];
    const float* mw2  = (const float*)d_in[5];
    const float* mb2  = (const float*)d_in[6];
    const float* nw1  = (const float*)d_in[7];
    const float* nb1  = (const float*)d_in[8];
    const float* nw2  = (const float*)d_in[9];
    const float* nb2  = (const float*)d_in[10];
    const float* m2w1 = (const float*)d_in[11];
    const float* m2b1 = (const float*)d_in[12];
    const float* m2w2 = (const float*)d_in[13];
    const float* m2b2 = (const float*)d_in[14];
    const float* n2w1 = (const float*)d_in[15];
    const float* n2b1 = (const float*)d_in[16];
    const float* n2w2 = (const float*)d_in[17];
    const float* n2b2 = (const float*)d_in[18];
    float* out = (float*)d_out;

    float* fws   = (float*)d_ws;
    float* UX1   = fws;                   // 10000*256
    float* UX2   = fws + 2560000;         // 10000*256
    float* proj  = fws + 5120000;         // 10000*2
    float* maskv = fws + 5140000;         // 10000
    float* eas   = fws + 5150016;         // 150000
    float* M1    = fws + 5300016;         // 128*128
    float* M2    = fws + 5316400;         // 128*128
    float* WH    = fws + 5332784;         // 128*256
    float* v1    = fws + 5365552;         // 128
    float* v2    = fws + 5365680;         // 128
    float* bu2   = fws + 5365808;         // 128
    float* bx2   = fws + 5365936;         // 128
    int*   cnt   = (int*)(fws + 5366064);
    int*   fillc = cnt + N_NODES;
    int*   eoff  = fillc + N_NODES;
    // Bt aliases UX2: Bt (1.28 MB) is only live scanfold->fillgemm; UX2 is
    // written (fully) and read only inside tail16, after Bt is dead.
    u16*   Bt    = (u16*)(fws + 2560000); // 3*256*832 bf16 bits

    // L1-2: zero cnt, parallel histogram
    hipMemsetAsync(cnt, 0, N_NODES * sizeof(int), stream);
    count_kernel<<<EBLOCKS, 256, 0, stream>>>(idxs, cnt, E_EDGES);

    // L3: prefix-scan (block 0) + weight folds (1..40) + B bf16x3 split (41..56)
    scanfold_kernel<<<57, 256, 0, stream>>>(mw2, mb2, nw1, nb2, nw2,
                                            m2w1, m2b1, m2w2, m2b2, n2w1, n2b1,
                                            M1, M2, WH, v1, v2, bu2, bx2,
                                            cnt, eoff, maskv, fillc, mw1, Bt);

    // L4: MFMA GEMM (626 blocks, first = LPT) + CSR fill (587 blocks)
    fillgemm_kernel<<<GEMMB + EBLOCKS, 256, 0, stream>>>(
        idxs, eatt, eoff, fillc, eas,
        x, Bt, mb1, nb1, v1, maskv, UX1);

    // L5: tail at 16 rows/block, 625 blocks, 512 threads
    tail16_kernel<<<625, 512, 0, stream>>>(UX1, mw1 + 784 * 128, eas, eoff, cnt, maskv,
                                           M1, WH, bu2, bx2, v2,
                                           m2w1 + 128 * 128, M2,
                                           n2w2, n2b2,
                                           UX2, proj);

    // L6: per-edge squared distances
    dist_kernel<<<EBLOCKS, 256, 0, stream>>>(proj, idxs, out, E_EDGES);
}

// Round 8
// 253.663 us; speedup vs baseline: 1.1738x; 1.1738x over previous
//
#include <hip/hip_runtime.h>

#define N_NODES 10000
#define E_EDGES 150000
#define KNB     15
#define EBLOCKS 587    // ceil(E/256)
#define GEMMB   1252   // 313 rowBlks(32 rows) x 4 colBlks(64 cols)
#define KPAD    832    // 784 padded to 13*64
#define PLSTR   212992 // Bt plane stride = 256*832 (u16)

typedef unsigned short u16;
typedef __bf16 bf16x8 __attribute__((ext_vector_type(8)));
typedef float  f32x4  __attribute__((ext_vector_type(4)));
typedef unsigned short u16x8 __attribute__((ext_vector_type(8)));

// ---------------------------------------------------------------------------
// Exact-ish bf16x3 split: a ~= hi + mid + lo. hi is RNE bf16 (Veltkamp step is
// exact in fp32), mid/lo truncated. Residual ~2^-25*|a|; dropped cross terms
// (mid*lo etc.) ~2^-26 => fp32-level accuracy with 6 MFMA terms (p+q<=2).
// ---------------------------------------------------------------------------
__device__ __forceinline__ void split3(float a, u16& h, u16& m, u16& l) {
    unsigned u = __float_as_uint(a);
    unsigned t = u + 0x7FFFu + ((u >> 16) & 1u);
    h = (u16)(t >> 16);
    float r1 = a - __uint_as_float(t & 0xFFFF0000u);
    unsigned u1 = __float_as_uint(r1);
    m = (u16)(u1 >> 16);
    float r2 = r1 - __uint_as_float(u1 & 0xFFFF0000u);
    l = (u16)(__float_as_uint(r2) >> 16);
}

// ---------------------------------------------------------------------------
// CSR count: parallel global atomics — NEVER single-block this (R7 lesson).
// ---------------------------------------------------------------------------
__global__ void count_kernel(const int* __restrict__ idxs, int* __restrict__ cnt, int e) {
    int i = blockIdx.x * blockDim.x + threadIdx.x;
    if (i < e) atomicAdd(&cnt[idxs[i]], 1);
}

// ---------------------------------------------------------------------------
// gemm_tile2 (MR=2) — weight-space folds only
// ---------------------------------------------------------------------------
__device__ __forceinline__
void gemm_tile2(const float* __restrict__ A, int K,
                const float* __restrict__ Blo, const float* __restrict__ Bhi, int ldB,
                float* __restrict__ C, int ldC, int M,
                int rowBlk, int colBlk) {
    __shared__ float As2[16][34];
    __shared__ float Bs2[16][64];
    int tid = threadIdx.x;
    int tn  = tid & 15, tm = tid >> 4;
    int arow = tid >> 3, acB = (tid & 7) << 1;
    int brow = tid >> 4, bcol = (tid & 15) << 2;
    int rowBase = rowBlk * 32, colBase = colBlk * 64;

    bool half = (Bhi != nullptr) && (colBase >= 128);
    const float* B = half ? Bhi : Blo;
    int bj = colBase - (half ? 128 : 0) + bcol;

    float2 av; float4 bv;
    auto loadA = [&](int k0, float2& dst) {
        int gr = rowBase + arow;
        if (gr < M) dst = *(const float2*)(A + (size_t)gr * K + k0 + acB);
        else { dst.x = dst.y = 0.f; }
    };
    auto loadB = [&](int k0, float4& dst) {
        dst = *(const float4*)(B + (size_t)(k0 + brow) * ldB + bj);
    };
    loadA(0, av); loadB(0, bv);

    float acc[2][4] = {};
    for (int k0 = 0; k0 < K; k0 += 16) {
        __syncthreads();
        As2[acB + 0][arow] = av.x; As2[acB + 1][arow] = av.y;
        *(float4*)&Bs2[brow][bcol] = bv;
        __syncthreads();
        if (k0 + 16 < K) { loadA(k0 + 16, av); loadB(k0 + 16, bv); }
#pragma unroll
        for (int k = 0; k < 16; ++k) {
            float4 b = *(const float4*)&Bs2[k][tn << 2];
            float2 a = *(const float2*)&As2[k][tm << 1];
            acc[0][0] = fmaf(a.x, b.x, acc[0][0]); acc[0][1] = fmaf(a.x, b.y, acc[0][1]);
            acc[0][2] = fmaf(a.x, b.z, acc[0][2]); acc[0][3] = fmaf(a.x, b.w, acc[0][3]);
            acc[1][0] = fmaf(a.y, b.x, acc[1][0]); acc[1][1] = fmaf(a.y, b.y, acc[1][1]);
            acc[1][2] = fmaf(a.y, b.z, acc[1][2]); acc[1][3] = fmaf(a.y, b.w, acc[1][3]);
        }
    }
#pragma unroll
    for (int i = 0; i < 2; ++i) {
        int row = rowBase + tm * 2 + i;
        if (row >= M) continue;
#pragma unroll
        for (int j = 0; j < 4; ++j)
            C[(size_t)row * ldC + colBase + (tn << 2) + j] = acc[i][j];
    }
}

// ---------------------------------------------------------------------------
// scanfold: block 0 = prefix-scan of cnt; blocks 1..40 = weight folds;
// blocks 41..56 = bf16x3 split + transpose of [mw1|nw1] (rows 0..783, zero-pad
// to 832) into Bt[3][256][832] (bf16 bits, Bt[p][col][k] = B[k][col]).
// ---------------------------------------------------------------------------
__global__ __launch_bounds__(256)
void scanfold_kernel(const float* __restrict__ mw2, const float* __restrict__ mb2,
                     const float* __restrict__ nw1, const float* __restrict__ nb2,
                     const float* __restrict__ nw2,
                     const float* __restrict__ m2w1, const float* __restrict__ m2b1,
                     const float* __restrict__ m2w2, const float* __restrict__ m2b2,
                     const float* __restrict__ n2w1, const float* __restrict__ n2b1,
                     float* __restrict__ M1, float* __restrict__ M2,
                     float* __restrict__ WH,
                     float* __restrict__ v1, float* __restrict__ v2,
                     float* __restrict__ bu2, float* __restrict__ bx2,
                     const int* __restrict__ cnt, int* __restrict__ eoff,
                     float* __restrict__ maskv, int* __restrict__ fillc,
                     const float* __restrict__ mw1, u16* __restrict__ Bt) {
    int b = blockIdx.x;
    if (b >= 41) {
        // ---- bsplit: 16 cols per block, LDS transpose then split3 ----
        __shared__ float Lt[KPAD][17];
        int b2 = b - 41;
        int colBase = b2 * 16;
        const float* S = (colBase < 128) ? mw1 : nw1;
        int sc = colBase & 127;
        int tid = threadIdx.x;
        for (int i = 0; i < 52; ++i) {
            int row = (tid >> 4) + i * 16;
            Lt[row][tid & 15] = (row < 784) ? S[(size_t)row * 128 + sc + (tid & 15)] : 0.f;
        }
        __syncthreads();
        int col = tid >> 4, o = tid & 15;
        size_t dbase = (size_t)(colBase + col) * KPAD;
        for (int o2 = o; o2 < 104; o2 += 16) {
            u16 hs[8], ms[8], ls[8];
#pragma unroll
            for (int e = 0; e < 8; ++e) split3(Lt[o2 * 8 + e][col], hs[e], ms[e], ls[e]);
            auto pk = [](const u16* s) {
                uint4 v;
                v.x = s[0] | ((unsigned)s[1] << 16); v.y = s[2] | ((unsigned)s[3] << 16);
                v.z = s[4] | ((unsigned)s[5] << 16); v.w = s[6] | ((unsigned)s[7] << 16);
                return v;
            };
            *(uint4*)(Bt +           dbase + o2 * 8) = pk(hs);
            *(uint4*)(Bt + PLSTR   + dbase + o2 * 8) = pk(ms);
            *(uint4*)(Bt + 2*PLSTR + dbase + o2 * 8) = pk(ls);
        }
        return;
    }
    if (b == 0) {
        __shared__ int ssum[256];
        int tid = threadIdx.x;
        const int CH = 40;
        int base = tid * CH;
        int v[CH]; int s = 0;
#pragma unroll
        for (int q = 0; q < CH; ++q) {
            int i = base + q;
            v[q] = (i < N_NODES) ? cnt[i] : 0;
            s += v[q];
        }
        ssum[tid] = s;
        __syncthreads();
        for (int off = 1; off < 256; off <<= 1) {
            int t = (tid >= off) ? ssum[tid - off] : 0;
            __syncthreads();
            ssum[tid] += t;
            __syncthreads();
        }
        int ex = ssum[tid] - s;
#pragma unroll
        for (int q = 0; q < CH; ++q) {
            int i = base + q;
            if (i < N_NODES) {
                eoff[i]  = ex;
                maskv[i] = (v[q] > 0) ? 1.f : 0.f;
                fillc[i] = 0;
                ex += v[q];
            }
        }
        return;
    }
    b -= 1;
    if (b < 8) {
        gemm_tile2(mw2, 784, nw1 + 784 * 128, nullptr, 128, M1, 128, 128, b >> 1, b & 1);
    } else if (b < 16) {
        int t = b - 8;
        gemm_tile2(m2w2, 128, n2w1 + 128 * 128, nullptr, 128, M2, 128, 128, t >> 1, t & 1);
    } else if (b < 32) {
        int t = b - 16;
        gemm_tile2(nw2, 128, m2w1, n2w1, 128, WH, 256, 128, t >> 2, t & 3);
    } else {
        __shared__ float red[256];
        int t  = (b - 32) >> 1;
        int j  = ((b - 32) & 1) * 64 + (threadIdx.x & 63);
        int kq = threadIdx.x >> 6;
        const float* bvec; const float* Bv; const float* add; float* out; int Kv;
        if (t == 0)      { bvec = mb2;  Bv = nw1 + 784 * 128;  add = nullptr; out = v1;  Kv = 784; }
        else if (t == 1) { bvec = m2b2; Bv = n2w1 + 128 * 128; add = nullptr; out = v2;  Kv = 128; }
        else if (t == 2) { bvec = nb2;  Bv = m2w1;             add = m2b1;    out = bu2; Kv = 128; }
        else             { bvec = nb2;  Bv = n2w1;             add = n2b1;    out = bx2; Kv = 128; }
        float acc = 0.f;
        for (int k = kq; k < Kv; k += 4) acc = fmaf(bvec[k], Bv[k * 128 + j], acc);
        red[threadIdx.x] = acc;
        __syncthreads();
        if (threadIdx.x < 64) {
            float tot = red[threadIdx.x] + red[threadIdx.x + 64] +
                        red[threadIdx.x + 128] + red[threadIdx.x + 192];
            out[j] = tot + (add ? add[j] : 0.f);
        }
    }
}

// ---------------------------------------------------------------------------
// MFMA bf16x3 GEMM tile: 32 rows x 64 cols, BK=64, B direct global->reg.
// R7 lesson: every schedule variant (R2-R6) pinned at 69-81us with pipe-util
// ~= occupancy — TLP-starved at 2.45 waves/SIMD (626-block grid). Quarter-
// width col-tiles double the grid to 1252 blocks = 4.9 waves/SIMD; B traffic
// unchanged (L2-resident Bt), A re-read 4x (+63MB ~ +2us). Per-wave B state
// collapses to 6 frags/set so the R5 ping-pong fits in a 128-VGPR budget
// (launch_bounds(256,4)). A in LDS per-wave contiguous (R4: 0 conflicts);
// FULLY SCALARIZED (R1 lesson).
// ---------------------------------------------------------------------------
#define MF(a, b, c) __builtin_amdgcn_mfma_f32_16x16x32_bf16((a), (b), (c), 0, 0, 0)

__device__ __forceinline__
void gemm_mfma(const float* __restrict__ A, const u16* __restrict__ Bt,
               const float* __restrict__ biasLo, const float* __restrict__ biasHi,
               const float* __restrict__ vhi, const float* __restrict__ rowmask,
               float* __restrict__ C, int gb) {
    __shared__ u16 As[3][2][2][64][8];   // 12 KB [plane][kt][rowfrag][lane][e]
    const int tid  = threadIdx.x;
    const int lane = tid & 63, w = tid >> 6;
    const int rb = gb >> 2, cbq = gb & 3;
    const int rowBase = rb * 32, colBase = cbq * 64;
    const bool hi = cbq >= 2;
    u16* const AsB = &As[0][0][0][0][0];

    // ---- A staging: wave w -> (kt=w>>1, rf=w&1); lane l -> row rf*16+(l&15),
    //      k-octet l>>4 within the kt-half ----
    const int skt = w >> 1, srf = w & 1;
    const int aoff = skt * 32 + ((lane >> 4) << 3);     // k offset in 64-tile
    int arow = rowBase + srf * 16 + (lane & 15);
    if (arow > N_NODES - 1) arow = N_NODES - 1;
    const float* Ap = A + (size_t)arow * 784;
    u16* aDst = AsB + skt * 1024 + srf * 512 + (lane << 3);   // +2048/plane

    // ---- B fragment base: this wave's 16 cols, this lane's (col, k-octet) --
    const u16* Bp = Bt + (size_t)(colBase + w * 16 + (lane & 15)) * KPAD
                       + ((lane >> 4) << 3);
    // frag(pl, kt) = Bp + pl*PLSTR + kt*32 + k0

    float4 av0, av1;
    u16x8 a3h, a3m, a3l;

#define ALOAD(k0) { int kk = (k0) + aoff; \
    if (kk < 784) { av0 = *(const float4*)(Ap + kk); av1 = *(const float4*)(Ap + kk + 4); } \
    else { av0.x=av0.y=av0.z=av0.w=0.f; av1 = av0; } }
#define ASPLIT() { u16 h, m, l; \
    split3(av0.x, h, m, l); a3h[0] = h; a3m[0] = m; a3l[0] = l; \
    split3(av0.y, h, m, l); a3h[1] = h; a3m[1] = m; a3l[1] = l; \
    split3(av0.z, h, m, l); a3h[2] = h; a3m[2] = m; a3l[2] = l; \
    split3(av0.w, h, m, l); a3h[3] = h; a3m[3] = m; a3l[3] = l; \
    split3(av1.x, h, m, l); a3h[4] = h; a3m[4] = m; a3l[4] = l; \
    split3(av1.y, h, m, l); a3h[5] = h; a3m[5] = m; a3l[5] = l; \
    split3(av1.z, h, m, l); a3h[6] = h; a3m[6] = m; a3l[6] = l; \
    split3(av1.w, h, m, l); a3h[7] = h; a3m[7] = m; a3l[7] = l; }

// two named B register sets (ping-pong), 6 frags each: (plane h/m/l) x (kt 0/1)
#define BDECL(S) bf16x8 S##h0, S##h1, S##m0, S##m1, S##l0, S##l1;
#define BLOAD(S, k0) \
    S##h0 = *(const bf16x8*)(Bp + (k0)); \
    S##h1 = *(const bf16x8*)(Bp + (k0) + 32); \
    S##m0 = *(const bf16x8*)(Bp + (k0) + PLSTR); \
    S##m1 = *(const bf16x8*)(Bp + (k0) + PLSTR + 32); \
    S##l0 = *(const bf16x8*)(Bp + (k0) + 2*PLSTR); \
    S##l1 = *(const bf16x8*)(Bp + (k0) + 2*PLSTR + 32);

#define DOMFMA(S) { \
    { /* KT = 0 */ \
        bf16x8 a0h = *(const bf16x8*)(aFr); \
        bf16x8 a1h = *(const bf16x8*)(aFr + 512); \
        bf16x8 a0m = *(const bf16x8*)(aFr + 2048); \
        bf16x8 a1m = *(const bf16x8*)(aFr + 2560); \
        bf16x8 a0l = *(const bf16x8*)(aFr + 4096); \
        bf16x8 a1l = *(const bf16x8*)(aFr + 4608); \
        acc0 = MF(a0h, S##h0, acc0); acc1 = MF(a1h, S##h0, acc1); \
        acc0 = MF(a0m, S##h0, acc0); acc1 = MF(a1m, S##h0, acc1); \
        acc0 = MF(a0l, S##h0, acc0); acc1 = MF(a1l, S##h0, acc1); \
        acc0 = MF(a0h, S##m0, acc0); acc1 = MF(a1h, S##m0, acc1); \
        acc0 = MF(a0m, S##m0, acc0); acc1 = MF(a1m, S##m0, acc1); \
        acc0 = MF(a0h, S##l0, acc0); acc1 = MF(a1h, S##l0, acc1); \
    } \
    { /* KT = 1 */ \
        bf16x8 a0h = *(const bf16x8*)(aFr + 1024); \
        bf16x8 a1h = *(const bf16x8*)(aFr + 1536); \
        bf16x8 a0m = *(const bf16x8*)(aFr + 3072); \
        bf16x8 a1m = *(const bf16x8*)(aFr + 3584); \
        bf16x8 a0l = *(const bf16x8*)(aFr + 5120); \
        bf16x8 a1l = *(const bf16x8*)(aFr + 5632); \
        acc0 = MF(a0h, S##h1, acc0); acc1 = MF(a1h, S##h1, acc1); \
        acc0 = MF(a0m, S##h1, acc0); acc1 = MF(a1m, S##h1, acc1); \
        acc0 = MF(a0l, S##h1, acc0); acc1 = MF(a1l, S##h1, acc1); \
        acc0 = MF(a0h, S##m1, acc0); acc1 = MF(a1h, S##m1, acc1); \
        acc0 = MF(a0m, S##m1, acc0); acc1 = MF(a1m, S##m1, acc1); \
        acc0 = MF(a0h, S##l1, acc0); acc1 = MF(a1h, S##l1, acc1); \
    } }

// one k-tile iteration: stage A(t), prefetch A/B(t+1), compute with CUR set
#define ITER(CUR, NXT, T) { \
    __syncthreads(); \
    *(u16x8*)(aDst)        = a3h; \
    *(u16x8*)(aDst + 2048) = a3m; \
    *(u16x8*)(aDst + 4096) = a3l; \
    __syncthreads(); \
    if ((T) < 12) { ALOAD(((T) + 1) << 6) BLOAD(NXT, ((T) + 1) << 6) } \
    DOMFMA(CUR) \
    if ((T) < 12) { ASPLIT() } }

    f32x4 acc0 = {0.f, 0.f, 0.f, 0.f};
    f32x4 acc1 = acc0;

    const u16* aFr = AsB + (lane << 3);   // +512/rf, +1024/kt, +2048/plane

    BDECL(p) BDECL(q)
    ALOAD(0) ASPLIT()
    BLOAD(p, 0)

    ITER(p, q, 0)  ITER(q, p, 1)  ITER(p, q, 2)  ITER(q, p, 3)
    ITER(p, q, 4)  ITER(q, p, 5)  ITER(p, q, 6)  ITER(q, p, 7)
    ITER(p, q, 8)  ITER(q, p, 9)  ITER(p, q, 10) ITER(q, p, 11)
    ITER(p, q, 12)

#undef ITER
#undef DOMFMA
#undef BLOAD
#undef BDECL
#undef ALOAD
#undef ASPLIT

    // epilogue: C row = (lane>>4)*4+r, col = lane&15 within each 16x16 frag
    const float* bias = hi ? biasHi : biasLo;
#define EPI(rf, ACC) { \
        const int col = colBase + w * 16 + (lane & 15); \
        const int cj  = col & 127; \
        const float bb = bias[cj]; \
        const float vh = hi ? vhi[cj] : 0.f; \
        const int rbase = rowBase + (rf) * 16 + ((lane >> 4) << 2); \
        _Pragma("unroll") \
        for (int rr = 0; rr < 4; ++rr) { \
            int row = rbase + rr; \
            if (row < N_NODES) { \
                float v = ACC[rr] + bb; \
                if (hi) v = fmaf(rowmask[row], vh, v); \
                C[(size_t)row * 256 + col] = v; \
            } } }
    EPI(0, acc0) EPI(1, acc1)
#undef EPI
}

// ---------------------------------------------------------------------------
// fillgemm: blocks [0,GEMMB) = MFMA GEMM (long blocks first, LPT);
//           blocks [GEMMB, GEMMB+EBLOCKS) = CSR fill.
// launch_bounds(256,4): 4 waves/EU target caps VGPR at 128 — grid now offers
// 4.9 waves/SIMD and the allocator must not block that (R7 TLP fix).
// ---------------------------------------------------------------------------
__global__ __launch_bounds__(256, 4)
void fillgemm_kernel(const int* __restrict__ idxs, const float* __restrict__ ea,
                     const int* __restrict__ eoff, int* __restrict__ fillc,
                     float* __restrict__ eas,
                     const float* __restrict__ A, const u16* __restrict__ Bt,
                     const float* __restrict__ biasLo, const float* __restrict__ biasHi,
                     const float* __restrict__ vhi, const float* __restrict__ rowmask,
                     float* __restrict__ C) {
    int gb = blockIdx.x;
    if (gb < GEMMB) {
        gemm_mfma(A, Bt, biasLo, biasHi, vhi, rowmask, C, gb);
        return;
    }
    int i = (gb - GEMMB) * 256 + threadIdx.x;
    if (i < E_EDGES) {
        int s = idxs[i];
        int p = atomicAdd(&fillc[s], 1);
        eas[eoff[s] + p] = ea[i];
    }
}

// ---------------------------------------------------------------------------
// tail16 @ 512 threads (R2 lesson: tail is per-block-latency-bound — all 625
// blocks co-resident, so duration == one block's serial chain).
// ---------------------------------------------------------------------------
__global__ __launch_bounds__(512, 4)
void tail16_kernel(const float* __restrict__ UX1, const float* __restrict__ w1last,
                   const float* __restrict__ eas, const int* __restrict__ eoff,
                   const int* __restrict__ cnt, const float* __restrict__ maskv,
                   const float* __restrict__ M1, const float* __restrict__ WH,
                   const float* __restrict__ bu2, const float* __restrict__ bx2,
                   const float* __restrict__ v2,
                   const float* __restrict__ w2last, const float* __restrict__ M2,
                   const float* __restrict__ pw, const float* __restrict__ pb,
                   float* __restrict__ UX2, float* __restrict__ proj) {
    __shared__ float Bs[16][264];    // B staging (all GEMM phases)
    __shared__ float mhT[128][18];   // msg means [k][m]
    __shared__ float ts[16][132];    // z1 rows
    __shared__ float ebuf[1024];     // CSR edge window
    int rowBase = blockIdx.x * 16;   // 625*16 = 10000 exact
    int tid = threadIdx.x;
    int tr  = tid >> 5;              // 0..15 — this thread's GEMM row
    int tn  = tid & 31;
    int c4  = tn << 2;

    auto msg_phase = [&](const float* __restrict__ U, const float* __restrict__ wl) {
        int d = tid & 127, grp = tid >> 7;   // grp 0..3, wave-uniform
        float w = wl[d];
        float uu[4], sum[4];
        int es[4], ec[4];
#pragma unroll
        for (int it = 0; it < 4; ++it) {
            int n  = rowBase + it * 4 + grp;
            ec[it] = cnt[n];
            es[it] = eoff[n];
            uu[it] = U[(size_t)n * 256 + d];
            sum[it] = 0.f;
        }
        int ebase = eoff[rowBase];
        int eend  = (rowBase + 16 < N_NODES) ? eoff[rowBase + 16] : E_EDGES;
        for (int w0 = ebase; w0 < eend; w0 += 1024) {
            int wlen = min(1024, eend - w0);
            __syncthreads();
            for (int q = tid; q < wlen; q += 512) ebuf[q] = eas[w0 + q];
            __syncthreads();
#pragma unroll
            for (int it = 0; it < 4; ++it) {
                int lo = max(es[it], w0), hiE = min(es[it] + ec[it], w0 + wlen);
                for (int e = lo; e < hiE; ++e)
                    sum[it] += fmaxf(fmaf(ebuf[e - w0], w, uu[it]), 0.f);
            }
        }
#pragma unroll
        for (int it = 0; it < 4; ++it)
            mhT[d][it * 4 + grp] = (ec[it] > 0) ? sum[it] / (float)ec[it] : 0.f;
    };

    // ===== msg1 =====
    msg_phase(UX1, w1last);

    // ===== phase1: ts = relu(xn1 + mhT @ M1), 16x128, 1 row/thread =====
    {
        float a0 = 0.f, a1 = 0.f, a2 = 0.f, a3 = 0.f;
        float4 bv = *(const float4*)(M1 + (size_t)tr * 128 + c4);
        for (int k0 = 0; k0 < 128; k0 += 16) {
            __syncthreads();                 // Bs free + (k0=0) mhT ready
            *(float4*)&Bs[tr][c4] = bv;
            __syncthreads();
            if (k0 + 16 < 128)
                bv = *(const float4*)(M1 + (size_t)(k0 + 16 + tr) * 128 + c4);
#pragma unroll
            for (int k = 0; k < 16; ++k) {
                float a = mhT[k0 + k][tr];
                float4 b = *(const float4*)&Bs[k][c4];
                a0 = fmaf(a, b.x, a0); a1 = fmaf(a, b.y, a1);
                a2 = fmaf(a, b.z, a2); a3 = fmaf(a, b.w, a3);
            }
        }
        int row = rowBase + tr;
        float4 xn = *(const float4*)(UX1 + (size_t)row * 256 + 128 + c4);
        float4 o;
        o.x = fmaxf(a0 + xn.x, 0.f);
        o.y = fmaxf(a1 + xn.y, 0.f);
        o.z = fmaxf(a2 + xn.z, 0.f);
        o.w = fmaxf(a3 + xn.w, 0.f);
        *(float4*)&ts[tr][c4] = o;
    }

    // ===== phase2: UX2 = ts @ WH + bias (+maskv*v2 on hi), 16x256 =====
    {
        float u0 = 0.f, u1 = 0.f, u2 = 0.f, u3 = 0.f;
        float x0 = 0.f, x1 = 0.f, x2 = 0.f, x3 = 0.f;
        int c8 = tn << 3;
        float4 bva = *(const float4*)(WH + (size_t)tr * 256 + c8);
        float4 bvb = *(const float4*)(WH + (size_t)tr * 256 + c8 + 4);
        for (int k0 = 0; k0 < 128; k0 += 16) {
            __syncthreads();                 // orders ts writes / Bs reuse
            *(float4*)&Bs[tr][c8]     = bva;
            *(float4*)&Bs[tr][c8 + 4] = bvb;
            __syncthreads();
            if (k0 + 16 < 128) {
                bva = *(const float4*)(WH + (size_t)(k0 + 16 + tr) * 256 + c8);
                bvb = *(const float4*)(WH + (size_t)(k0 + 16 + tr) * 256 + c8 + 4);
            }
#pragma unroll
            for (int k = 0; k < 16; ++k) {
                float a = ts[tr][k0 + k];
                float4 b0 = *(const float4*)&Bs[k][c4];          // cols 4tn..   (u half)
                float4 b1 = *(const float4*)&Bs[k][c4 + 128];    // cols 128+4tn (x half)
                u0 = fmaf(a, b0.x, u0); u1 = fmaf(a, b0.y, u1);
                u2 = fmaf(a, b0.z, u2); u3 = fmaf(a, b0.w, u3);
                x0 = fmaf(a, b1.x, x0); x1 = fmaf(a, b1.y, x1);
                x2 = fmaf(a, b1.z, x2); x3 = fmaf(a, b1.w, x3);
            }
        }
        int row = rowBase + tr;
        float rm = maskv[row];
        float4 o0, o1;
        o0.x = u0 + bu2[c4 + 0]; o0.y = u1 + bu2[c4 + 1];
        o0.z = u2 + bu2[c4 + 2]; o0.w = u3 + bu2[c4 + 3];
        o1.x = fmaf(rm, v2[c4 + 0], x0 + bx2[c4 + 0]);
        o1.y = fmaf(rm, v2[c4 + 1], x1 + bx2[c4 + 1]);
        o1.z = fmaf(rm, v2[c4 + 2], x2 + bx2[c4 + 2]);
        o1.w = fmaf(rm, v2[c4 + 3], x3 + bx2[c4 + 3]);
        float* orow = UX2 + (size_t)row * 256;
        *(float4*)(orow + c4)       = o0;
        *(float4*)(orow + 128 + c4) = o1;
    }
    __syncthreads();   // UX2 block-visible (own rows only are read below)

    // ===== msg2 =====
    msg_phase(UX2, w2last);

    // ===== phase4: z2 = relu(xn2 + mhT@M2); proj = z2@pw + pb =====
    {
        float a0 = 0.f, a1 = 0.f, a2 = 0.f, a3 = 0.f;
        float4 bv = *(const float4*)(M2 + (size_t)tr * 128 + c4);
        for (int k0 = 0; k0 < 128; k0 += 16) {
            __syncthreads();                 // orders msg2's mhT writes
            *(float4*)&Bs[tr][c4] = bv;
            __syncthreads();
            if (k0 + 16 < 128)
                bv = *(const float4*)(M2 + (size_t)(k0 + 16 + tr) * 128 + c4);
#pragma unroll
            for (int k = 0; k < 16; ++k) {
                float a = mhT[k0 + k][tr];
                float4 b = *(const float4*)&Bs[k][c4];
                a0 = fmaf(a, b.x, a0); a1 = fmaf(a, b.y, a1);
                a2 = fmaf(a, b.z, a2); a3 = fmaf(a, b.w, a3);
            }
        }
        int row = rowBase + tr;
        float4 xn = *(const float4*)(UX2 + (size_t)row * 256 + 128 + c4);
        float t0 = fmaxf(a0 + xn.x, 0.f);
        float t1 = fmaxf(a1 + xn.y, 0.f);
        float t2 = fmaxf(a2 + xn.z, 0.f);
        float t3 = fmaxf(a3 + xn.w, 0.f);
        float pp0 = fmaf(t3, pw[2*(c4+3)],   fmaf(t2, pw[2*(c4+2)],   fmaf(t1, pw[2*(c4+1)],   t0 * pw[2*c4])));
        float pp1 = fmaf(t3, pw[2*(c4+3)+1], fmaf(t2, pw[2*(c4+2)+1], fmaf(t1, pw[2*(c4+1)+1], t0 * pw[2*c4+1])));
        for (int off = 16; off > 0; off >>= 1) {
            pp0 += __shfl_xor(pp0, off, 64);
            pp1 += __shfl_xor(pp1, off, 64);
        }
        if (tn == 0) {
            proj[2 * row]     = pp0 + pb[0];
            proj[2 * row + 1] = pp1 + pb[1];
        }
    }
}

__global__ void dist_kernel(const float* __restrict__ proj, const int* __restrict__ idxs,
                            float* __restrict__ out, int e) {
    int i = blockIdx.x * blockDim.x + threadIdx.x;
    if (i >= e) return;
    int n = i / KNB;
    int m = idxs[i];
    float2 pn = *(const float2*)(proj + 2 * n);
    float2 pm = *(const float2*)(proj + 2 * m);
    float dx = pn.x - pm.x;
    float dy = pn.y - pm.y;
    out[i] = dx * dx + dy * dy;
}

// ---------------------------------------------------------------------------
extern "C" void kernel_launch(void* const* d_in, const int* in_sizes, int n_in,
                              void* d_out, int out_size, void* d_ws, size_t ws_size,
                              hipStream_t stream) {
    (void)in_sizes; (void)n_in; (void)out_size; (void)ws_size;
    const float* x    = (const float*)d_in[0];
    const float* eatt = (const float*)d_in[1];
    const int*   idxs = (const int*)d_in[2];
    const float* mw1  = (const float*)d_in[3];
    const float* mb1  = (const float*)d_in[4];
    const float* mw2  = (const float*)d_in[5];
    const float* mb2  = (const float*)d_in[6];
    const float* nw1  = (const float*)d_in[7];
    const float* nb1  = (const float*)d_in[8];
    const float* nw2  = (const float*)d_in[9];
    const float* nb2  = (const float*)d_in[10];
    const float* m2w1 = (const float*)d_in[11];
    const float* m2b1 = (const float*)d_in[12];
    const float* m2w2 = (const float*)d_in[13];
    const float* m2b2 = (const float*)d_in[14];
    const float* n2w1 = (const float*)d_in[15];
    const float* n2b1 = (const float*)d_in[16];
    const float* n2w2 = (const float*)d_in[17];
    const float* n2b2 = (const float*)d_in[18];
    float* out = (float*)d_out;

    float* fws   = (float*)d_ws;
    float* UX1   = fws;                   // 10000*256
    float* UX2   = fws + 2560000;         // 10000*256
    float* proj  = fws + 5120000;         // 10000*2
    float* maskv = fws + 5140000;         // 10000
    float* eas   = fws + 5150016;         // 150000
    float* M1    = fws + 5300016;         // 128*128
    float* M2    = fws + 5316400;         // 128*128
    float* WH    = fws + 5332784;         // 128*256
    float* v1    = fws + 5365552;         // 128
    float* v2    = fws + 5365680;         // 128
    float* bu2   = fws + 5365808;         // 128
    float* bx2   = fws + 5365936;         // 128
    int*   cnt   = (int*)(fws + 5366064);
    int*   fillc = cnt + N_NODES;
    int*   eoff  = fillc + N_NODES;
    // Bt aliases UX2: Bt (1.28 MB) is only live scanfold->fillgemm; UX2 is
    // written (fully) and read only inside tail16, after Bt is dead.
    u16*   Bt    = (u16*)(fws + 2560000); // 3*256*832 bf16 bits

    // L1-2: zero cnt, parallel histogram
    hipMemsetAsync(cnt, 0, N_NODES * sizeof(int), stream);
    count_kernel<<<EBLOCKS, 256, 0, stream>>>(idxs, cnt, E_EDGES);

    // L3: prefix-scan (block 0) + weight folds (1..40) + B bf16x3 split (41..56)
    scanfold_kernel<<<57, 256, 0, stream>>>(mw2, mb2, nw1, nb2, nw2,
                                            m2w1, m2b1, m2w2, m2b2, n2w1, n2b1,
                                            M1, M2, WH, v1, v2, bu2, bx2,
                                            cnt, eoff, maskv, fillc, mw1, Bt);

    // L4: MFMA GEMM (1252 blocks, first = LPT) + CSR fill (587 blocks)
    fillgemm_kernel<<<GEMMB + EBLOCKS, 256, 0, stream>>>(
        idxs, eatt, eoff, fillc, eas,
        x, Bt, mb1, nb1, v1, maskv, UX1);

    // L5: tail at 16 rows/block, 625 blocks, 512 threads
    tail16_kernel<<<625, 512, 0, stream>>>(UX1, mw1 + 784 * 128, eas, eoff, cnt, maskv,
                                           M1, WH, bu2, bx2, v2,
                                           m2w1 + 128 * 128, M2,
                                           n2w2, n2b2,
                                           UX2, proj);

    // L6: per-edge squared distances
    dist_kernel<<<EBLOCKS, 256, 0, stream>>>(proj, idxs, out, E_EDGES);
}

// Round 9
// 243.639 us; speedup vs baseline: 1.2221x; 1.0411x over previous
//
#include <hip/hip_runtime.h>

#define N_NODES 10000
#define E_EDGES 150000
#define KNB     15
#define EBLOCKS 587    // ceil(E/256)
#define GEMMB   1252   // 313 rowBlks(32 rows) x 4 colBlks(64 cols)
#define KPAD    800    // 784 padded to 25*32
#define PLSTR   204800 // Bt plane stride = 256*800 (u16)

typedef unsigned short u16;
typedef __bf16 bf16x8 __attribute__((ext_vector_type(8)));
typedef float  f32x4  __attribute__((ext_vector_type(4)));

// ---------------------------------------------------------------------------
// Exact-ish bf16x3 split: a ~= hi + mid + lo. hi is RNE bf16 (Veltkamp step is
// exact in fp32), mid/lo truncated. Residual ~2^-25*|a|; dropped cross terms
// (mid*lo etc.) ~2^-26 => fp32-level accuracy with 6 MFMA terms (p+q<=2).
// ---------------------------------------------------------------------------
__device__ __forceinline__ void split3(float a, u16& h, u16& m, u16& l) {
    unsigned u = __float_as_uint(a);
    unsigned t = u + 0x7FFFu + ((u >> 16) & 1u);
    h = (u16)(t >> 16);
    float r1 = a - __uint_as_float(t & 0xFFFF0000u);
    unsigned u1 = __float_as_uint(r1);
    m = (u16)(u1 >> 16);
    float r2 = r1 - __uint_as_float(u1 & 0xFFFF0000u);
    l = (u16)(__float_as_uint(r2) >> 16);
}

// async global->LDS, 16B per lane; dst is wave-uniform base, HW adds lane*16.
// Per-lane GLOBAL source address is allowed (guide m173/m151).
__device__ __forceinline__ void gl_lds16(const u16* g, u16* l) {
    __builtin_amdgcn_global_load_lds(
        (const __attribute__((address_space(1))) unsigned int*)(g),
        (__attribute__((address_space(3))) unsigned int*)(l),
        16, 0, 0);
}

// ---------------------------------------------------------------------------
// CSR count: parallel global atomics — NEVER single-block this (R7 lesson).
// ---------------------------------------------------------------------------
__global__ void count_kernel(const int* __restrict__ idxs, int* __restrict__ cnt, int e) {
    int i = blockIdx.x * blockDim.x + threadIdx.x;
    if (i < e) atomicAdd(&cnt[idxs[i]], 1);
}

// ---------------------------------------------------------------------------
// gemm_tile2 (MR=2) — weight-space folds only
// ---------------------------------------------------------------------------
__device__ __forceinline__
void gemm_tile2(const float* __restrict__ A, int K,
                const float* __restrict__ Blo, const float* __restrict__ Bhi, int ldB,
                float* __restrict__ C, int ldC, int M,
                int rowBlk, int colBlk) {
    __shared__ float As2[16][34];
    __shared__ float Bs2[16][64];
    int tid = threadIdx.x;
    int tn  = tid & 15, tm = tid >> 4;
    int arow = tid >> 3, acB = (tid & 7) << 1;
    int brow = tid >> 4, bcol = (tid & 15) << 2;
    int rowBase = rowBlk * 32, colBase = colBlk * 64;

    bool half = (Bhi != nullptr) && (colBase >= 128);
    const float* B = half ? Bhi : Blo;
    int bj = colBase - (half ? 128 : 0) + bcol;

    float2 av; float4 bv;
    auto loadA = [&](int k0, float2& dst) {
        int gr = rowBase + arow;
        if (gr < M) dst = *(const float2*)(A + (size_t)gr * K + k0 + acB);
        else { dst.x = dst.y = 0.f; }
    };
    auto loadB = [&](int k0, float4& dst) {
        dst = *(const float4*)(B + (size_t)(k0 + brow) * ldB + bj);
    };
    loadA(0, av); loadB(0, bv);

    float acc[2][4] = {};
    for (int k0 = 0; k0 < K; k0 += 16) {
        __syncthreads();
        As2[acB + 0][arow] = av.x; As2[acB + 1][arow] = av.y;
        *(float4*)&Bs2[brow][bcol] = bv;
        __syncthreads();
        if (k0 + 16 < K) { loadA(k0 + 16, av); loadB(k0 + 16, bv); }
#pragma unroll
        for (int k = 0; k < 16; ++k) {
            float4 b = *(const float4*)&Bs2[k][tn << 2];
            float2 a = *(const float2*)&As2[k][tm << 1];
            acc[0][0] = fmaf(a.x, b.x, acc[0][0]); acc[0][1] = fmaf(a.x, b.y, acc[0][1]);
            acc[0][2] = fmaf(a.x, b.z, acc[0][2]); acc[0][3] = fmaf(a.x, b.w, acc[0][3]);
            acc[1][0] = fmaf(a.y, b.x, acc[1][0]); acc[1][1] = fmaf(a.y, b.y, acc[1][1]);
            acc[1][2] = fmaf(a.y, b.z, acc[1][2]); acc[1][3] = fmaf(a.y, b.w, acc[1][3]);
        }
    }
#pragma unroll
    for (int i = 0; i < 2; ++i) {
        int row = rowBase + tm * 2 + i;
        if (row >= M) continue;
#pragma unroll
        for (int j = 0; j < 4; ++j)
            C[(size_t)row * ldC + colBase + (tn << 2) + j] = acc[i][j];
    }
}

// ---------------------------------------------------------------------------
// scanfold: block 0 = prefix-scan of cnt; blocks 1..40 = weight folds;
// blocks 41..56 = bf16x3 split + transpose of [mw1|nw1] (rows 0..783, zero-pad
// to 800) into Bt[3][256][800] (bf16 bits, Bt[p][col][k] = B[k][col]).
// ---------------------------------------------------------------------------
__global__ __launch_bounds__(256)
void scanfold_kernel(const float* __restrict__ mw2, const float* __restrict__ mb2,
                     const float* __restrict__ nw1, const float* __restrict__ nb2,
                     const float* __restrict__ nw2,
                     const float* __restrict__ m2w1, const float* __restrict__ m2b1,
                     const float* __restrict__ m2w2, const float* __restrict__ m2b2,
                     const float* __restrict__ n2w1, const float* __restrict__ n2b1,
                     float* __restrict__ M1, float* __restrict__ M2,
                     float* __restrict__ WH,
                     float* __restrict__ v1, float* __restrict__ v2,
                     float* __restrict__ bu2, float* __restrict__ bx2,
                     const int* __restrict__ cnt, int* __restrict__ eoff,
                     float* __restrict__ maskv, int* __restrict__ fillc,
                     const float* __restrict__ mw1, u16* __restrict__ Bt) {
    int b = blockIdx.x;
    if (b >= 41) {
        // ---- bsplit: 16 cols per block, LDS transpose then split3 ----
        __shared__ float Lt[KPAD][17];
        int b2 = b - 41;
        int colBase = b2 * 16;
        const float* S = (colBase < 128) ? mw1 : nw1;
        int sc = colBase & 127;
        int tid = threadIdx.x;
        for (int i = 0; i < 50; ++i) {
            int row = (tid >> 4) + i * 16;
            Lt[row][tid & 15] = (row < 784) ? S[(size_t)row * 128 + sc + (tid & 15)] : 0.f;
        }
        __syncthreads();
        int col = tid >> 4, o = tid & 15;
        size_t dbase = (size_t)(colBase + col) * KPAD;
        for (int o2 = o; o2 < 100; o2 += 16) {
            u16 hs[8], ms[8], ls[8];
#pragma unroll
            for (int e = 0; e < 8; ++e) split3(Lt[o2 * 8 + e][col], hs[e], ms[e], ls[e]);
            auto pk = [](const u16* s) {
                uint4 v;
                v.x = s[0] | ((unsigned)s[1] << 16); v.y = s[2] | ((unsigned)s[3] << 16);
                v.z = s[4] | ((unsigned)s[5] << 16); v.w = s[6] | ((unsigned)s[7] << 16);
                return v;
            };
            *(uint4*)(Bt +           dbase + o2 * 8) = pk(hs);
            *(uint4*)(Bt + PLSTR   + dbase + o2 * 8) = pk(ms);
            *(uint4*)(Bt + 2*PLSTR + dbase + o2 * 8) = pk(ls);
        }
        return;
    }
    if (b == 0) {
        __shared__ int ssum[256];
        int tid = threadIdx.x;
        const int CH = 40;
        int base = tid * CH;
        int v[CH]; int s = 0;
#pragma unroll
        for (int q = 0; q < CH; ++q) {
            int i = base + q;
            v[q] = (i < N_NODES) ? cnt[i] : 0;
            s += v[q];
        }
        ssum[tid] = s;
        __syncthreads();
        for (int off = 1; off < 256; off <<= 1) {
            int t = (tid >= off) ? ssum[tid - off] : 0;
            __syncthreads();
            ssum[tid] += t;
            __syncthreads();
        }
        int ex = ssum[tid] - s;
#pragma unroll
        for (int q = 0; q < CH; ++q) {
            int i = base + q;
            if (i < N_NODES) {
                eoff[i]  = ex;
                maskv[i] = (v[q] > 0) ? 1.f : 0.f;
                fillc[i] = 0;
                ex += v[q];
            }
        }
        return;
    }
    b -= 1;
    if (b < 8) {
        gemm_tile2(mw2, 784, nw1 + 784 * 128, nullptr, 128, M1, 128, 128, b >> 1, b & 1);
    } else if (b < 16) {
        int t = b - 8;
        gemm_tile2(m2w2, 128, n2w1 + 128 * 128, nullptr, 128, M2, 128, 128, t >> 1, t & 1);
    } else if (b < 32) {
        int t = b - 16;
        gemm_tile2(nw2, 128, m2w1, n2w1, 128, WH, 256, 128, t >> 2, t & 3);
    } else {
        __shared__ float red[256];
        int t  = (b - 32) >> 1;
        int j  = ((b - 32) & 1) * 64 + (threadIdx.x & 63);
        int kq = threadIdx.x >> 6;
        const float* bvec; const float* Bv; const float* add; float* out; int Kv;
        if (t == 0)      { bvec = mb2;  Bv = nw1 + 784 * 128;  add = nullptr; out = v1;  Kv = 784; }
        else if (t == 1) { bvec = m2b2; Bv = n2w1 + 128 * 128; add = nullptr; out = v2;  Kv = 128; }
        else if (t == 2) { bvec = nb2;  Bv = m2w1;             add = m2b1;    out = bu2; Kv = 128; }
        else             { bvec = nb2;  Bv = n2w1;             add = n2b1;    out = bx2; Kv = 128; }
        float acc = 0.f;
        for (int k = kq; k < Kv; k += 4) acc = fmaf(bvec[k], Bv[k * 128 + j], acc);
        red[threadIdx.x] = acc;
        __syncthreads();
        if (threadIdx.x < 64) {
            float tot = red[threadIdx.x] + red[threadIdx.x + 64] +
                        red[threadIdx.x + 128] + red[threadIdx.x + 192];
            out[j] = tot + (add ? add[j] : 0.f);
        }
    }
}

// ---------------------------------------------------------------------------
// MFMA bf16x3 GEMM tile: 32 rows x 64 cols, BK=32 — the m97 recipe.
// R8 lesson chain: R2/R5/R7 proved hipcc ALWAYS sinks register-resident B
// prefetch (VGPR=60/76/60), serializing L2 round trips in the MFMA stream.
// R6 proved global_load_lds works but 108KB LDS -> 1 block/CU killed TLP.
// This round: global_load_lds B (zero VGPR footprint, nothing to sink) at a
// geometry that keeps TLP: 18KB LDS (Bs 12K + As 6K), 1252-block grid,
// launch_bounds(256,4) -> ~4 blocks/CU. Per-iter drain is hidden by
// co-resident blocks (m97: 3 blocks/CU sufficed for 37% MfmaUtil).
// A in LDS (VALU split3 staging), B fragment-identity gl_lds.
// ---------------------------------------------------------------------------
#define MF(a, b, c) __builtin_amdgcn_mfma_f32_16x16x32_bf16((a), (b), (c), 0, 0, 0)

__device__ __forceinline__
void gemm_mfma(const float* __restrict__ A, const u16* __restrict__ Bt,
               const float* __restrict__ biasLo, const float* __restrict__ biasHi,
               const float* __restrict__ vhi, const float* __restrict__ rowmask,
               float* __restrict__ C, int gb) {
    __shared__ u16 As[3][2][64][8];   //  6 KB [plane][rowfrag][fraglane][e]
    __shared__ u16 Bs[3][4][64][8];   // 12 KB [plane][colfrag][lane][e]
    const int tid  = threadIdx.x;
    const int lane = tid & 63, w = tid >> 6;
    const int rb = gb >> 2, cbq = gb & 3;
    const int rowBase = rb * 32, colBase = cbq * 64;
    const bool hi = cbq >= 2;
    u16* const AsB = &As[0][0][0][0];
    u16* const BsB = &Bs[0][0][0][0];

    // ---- A staging: thread (w,l) -> rf=w&1, k-chunk=(w>>1)*4+(l>>4), row l&15
    const int srf   = w & 1;
    const int chunk = ((w >> 1) << 2) + (lane >> 4);  // 0..7, 4 k each
    const int aoff  = chunk << 2;                     // k offset 0..28
    int arow = rowBase + srf * 16 + (lane & 15);
    if (arow > N_NODES - 1) arow = N_NODES - 1;
    const float* Ap = A + (size_t)arow * 784;
    // frag elem (row r16, k): fraglane = r16 + 16*(k>>3), e = k&7
    u16* aDst = AsB + srf * 512 + (((lane & 15) + ((chunk >> 1) << 4)) << 3)
                    + ((chunk & 1) << 2);             // +1024 per plane

    // ---- B staging: 12 chunks (pl*4+cf), wave w owns chunks 3w..3w+2 ----
#define BSRC(c) ((size_t)((c) >> 2) * PLSTR + \
                 (size_t)(colBase + (((c) & 3) << 4) + (lane & 15)) * KPAD + \
                 ((lane >> 4) << 3))
    const int c0 = w * 3, c1 = w * 3 + 1, c2 = w * 3 + 2;
    const u16* bsrc0 = Bt + BSRC(c0);
    const u16* bsrc1 = Bt + BSRC(c1);
    const u16* bsrc2 = Bt + BSRC(c2);
    u16* bd0 = BsB + c0 * 512;
    u16* bd1 = BsB + c1 * 512;
    u16* bd2 = BsB + c2 * 512;
#undef BSRC

    float4 av;
    ushort4 a3h, a3m, a3l;

#define ALOAD(k0) { int kk = (k0) + aoff; \
    if (kk < 784) av = *(const float4*)(Ap + kk); \
    else { av.x = av.y = av.z = av.w = 0.f; } }
#define ASPLIT() { u16 h, m, l; \
    split3(av.x, h, m, l); a3h.x = h; a3m.x = m; a3l.x = l; \
    split3(av.y, h, m, l); a3h.y = h; a3m.y = m; a3l.y = l; \
    split3(av.z, h, m, l); a3h.z = h; a3m.z = m; a3l.z = l; \
    split3(av.w, h, m, l); a3h.w = h; a3m.w = m; a3l.w = l; }

    f32x4 acc0 = {0.f, 0.f, 0.f, 0.f};
    f32x4 acc1 = acc0;

    const u16* aFr = AsB + (lane << 3);              // +512/rf, +1024/plane
    const u16* bFr = BsB + (w << 9) + (lane << 3);   // wave's colfrag; +2048/plane

    ALOAD(0) ASPLIT()

    for (int t = 0; t < 25; ++t) {
        __syncthreads();                  // readers done: As/Bs writable
        const int k0 = t << 5;
        gl_lds16(bsrc0 + k0, bd0);        // B(t) -> LDS, zero VGPR
        gl_lds16(bsrc1 + k0, bd1);
        gl_lds16(bsrc2 + k0, bd2);
        *(ushort4*)(aDst)        = a3h;   // A(t) regs -> LDS
        *(ushort4*)(aDst + 1024) = a3m;
        *(ushort4*)(aDst + 2048) = a3l;
        __syncthreads();                  // drain: A(t),B(t) resident
        if (t < 24) ALOAD((t + 1) << 5)   // A(t+1) in flight under MFMA
        {
            bf16x8 a0h = *(const bf16x8*)(aFr);
            bf16x8 a1h = *(const bf16x8*)(aFr + 512);
            bf16x8 a0m = *(const bf16x8*)(aFr + 1024);
            bf16x8 a1m = *(const bf16x8*)(aFr + 1536);
            bf16x8 a0l = *(const bf16x8*)(aFr + 2048);
            bf16x8 a1l = *(const bf16x8*)(aFr + 2560);
            bf16x8 bh  = *(const bf16x8*)(bFr);
            bf16x8 bm  = *(const bf16x8*)(bFr + 2048);
            bf16x8 bl  = *(const bf16x8*)(bFr + 4096);
            acc0 = MF(a0h, bh, acc0); acc1 = MF(a1h, bh, acc1);
            acc0 = MF(a0m, bh, acc0); acc1 = MF(a1m, bh, acc1);
            acc0 = MF(a0l, bh, acc0); acc1 = MF(a1l, bh, acc1);
            acc0 = MF(a0h, bm, acc0); acc1 = MF(a1h, bm, acc1);
            acc0 = MF(a0m, bm, acc0); acc1 = MF(a1m, bm, acc1);
            acc0 = MF(a0h, bl, acc0); acc1 = MF(a1h, bl, acc1);
        }
        if (t < 24) ASPLIT()
    }
#undef ALOAD
#undef ASPLIT

    // epilogue: C row = (lane>>4)*4+r, col = lane&15 within each 16x16 frag
    const float* bias = hi ? biasHi : biasLo;
#define EPI(rf, ACC) { \
        const int col = colBase + w * 16 + (lane & 15); \
        const int cj  = col & 127; \
        const float bb = bias[cj]; \
        const float vh = hi ? vhi[cj] : 0.f; \
        const int rbase = rowBase + (rf) * 16 + ((lane >> 4) << 2); \
        _Pragma("unroll") \
        for (int rr = 0; rr < 4; ++rr) { \
            int row = rbase + rr; \
            if (row < N_NODES) { \
                float v = ACC[rr] + bb; \
                if (hi) v = fmaf(rowmask[row], vh, v); \
                C[(size_t)row * 256 + col] = v; \
            } } }
    EPI(0, acc0) EPI(1, acc1)
#undef EPI
}

// ---------------------------------------------------------------------------
// fillgemm: blocks [0,GEMMB) = MFMA GEMM (long blocks first, LPT);
//           blocks [GEMMB, GEMMB+EBLOCKS) = CSR fill.
// launch_bounds(256,4): 4 waves/EU -> 4 blocks/CU target (18KB LDS allows 8).
// ---------------------------------------------------------------------------
__global__ __launch_bounds__(256, 4)
void fillgemm_kernel(const int* __restrict__ idxs, const float* __restrict__ ea,
                     const int* __restrict__ eoff, int* __restrict__ fillc,
                     float* __restrict__ eas,
                     const float* __restrict__ A, const u16* __restrict__ Bt,
                     const float* __restrict__ biasLo, const float* __restrict__ biasHi,
                     const float* __restrict__ vhi, const float* __restrict__ rowmask,
                     float* __restrict__ C) {
    int gb = blockIdx.x;
    if (gb < GEMMB) {
        gemm_mfma(A, Bt, biasLo, biasHi, vhi, rowmask, C, gb);
        return;
    }
    int i = (gb - GEMMB) * 256 + threadIdx.x;
    if (i < E_EDGES) {
        int s = idxs[i];
        int p = atomicAdd(&fillc[s], 1);
        eas[eoff[s] + p] = ea[i];
    }
}

// ---------------------------------------------------------------------------
// tail16 @ 512 threads (R2 lesson: tail is per-block-latency-bound — all 625
// blocks co-resident, so duration == one block's serial chain).
// ---------------------------------------------------------------------------
__global__ __launch_bounds__(512, 4)
void tail16_kernel(const float* __restrict__ UX1, const float* __restrict__ w1last,
                   const float* __restrict__ eas, const int* __restrict__ eoff,
                   const int* __restrict__ cnt, const float* __restrict__ maskv,
                   const float* __restrict__ M1, const float* __restrict__ WH,
                   const float* __restrict__ bu2, const float* __restrict__ bx2,
                   const float* __restrict__ v2,
                   const float* __restrict__ w2last, const float* __restrict__ M2,
                   const float* __restrict__ pw, const float* __restrict__ pb,
                   float* __restrict__ UX2, float* __restrict__ proj) {
    __shared__ float Bs[16][264];    // B staging (all GEMM phases)
    __shared__ float mhT[128][18];   // msg means [k][m]
    __shared__ float ts[16][132];    // z1 rows
    __shared__ float ebuf[1024];     // CSR edge window
    int rowBase = blockIdx.x * 16;   // 625*16 = 10000 exact
    int tid = threadIdx.x;
    int tr  = tid >> 5;              // 0..15 — this thread's GEMM row
    int tn  = tid & 31;
    int c4  = tn << 2;

    auto msg_phase = [&](const float* __restrict__ U, const float* __restrict__ wl) {
        int d = tid & 127, grp = tid >> 7;   // grp 0..3, wave-uniform
        float w = wl[d];
        float uu[4], sum[4];
        int es[4], ec[4];
#pragma unroll
        for (int it = 0; it < 4; ++it) {
            int n  = rowBase + it * 4 + grp;
            ec[it] = cnt[n];
            es[it] = eoff[n];
            uu[it] = U[(size_t)n * 256 + d];
            sum[it] = 0.f;
        }
        int ebase = eoff[rowBase];
        int eend  = (rowBase + 16 < N_NODES) ? eoff[rowBase + 16] : E_EDGES;
        for (int w0 = ebase; w0 < eend; w0 += 1024) {
            int wlen = min(1024, eend - w0);
            __syncthreads();
            for (int q = tid; q < wlen; q += 512) ebuf[q] = eas[w0 + q];
            __syncthreads();
#pragma unroll
            for (int it = 0; it < 4; ++it) {
                int lo = max(es[it], w0), hiE = min(es[it] + ec[it], w0 + wlen);
                for (int e = lo; e < hiE; ++e)
                    sum[it] += fmaxf(fmaf(ebuf[e - w0], w, uu[it]), 0.f);
            }
        }
#pragma unroll
        for (int it = 0; it < 4; ++it)
            mhT[d][it * 4 + grp] = (ec[it] > 0) ? sum[it] / (float)ec[it] : 0.f;
    };

    // ===== msg1 =====
    msg_phase(UX1, w1last);

    // ===== phase1: ts = relu(xn1 + mhT @ M1), 16x128, 1 row/thread =====
    {
        float a0 = 0.f, a1 = 0.f, a2 = 0.f, a3 = 0.f;
        float4 bv = *(const float4*)(M1 + (size_t)tr * 128 + c4);
        for (int k0 = 0; k0 < 128; k0 += 16) {
            __syncthreads();                 // Bs free + (k0=0) mhT ready
            *(float4*)&Bs[tr][c4] = bv;
            __syncthreads();
            if (k0 + 16 < 128)
                bv = *(const float4*)(M1 + (size_t)(k0 + 16 + tr) * 128 + c4);
#pragma unroll
            for (int k = 0; k < 16; ++k) {
                float a = mhT[k0 + k][tr];
                float4 b = *(const float4*)&Bs[k][c4];
                a0 = fmaf(a, b.x, a0); a1 = fmaf(a, b.y, a1);
                a2 = fmaf(a, b.z, a2); a3 = fmaf(a, b.w, a3);
            }
        }
        int row = rowBase + tr;
        float4 xn = *(const float4*)(UX1 + (size_t)row * 256 + 128 + c4);
        float4 o;
        o.x = fmaxf(a0 + xn.x, 0.f);
        o.y = fmaxf(a1 + xn.y, 0.f);
        o.z = fmaxf(a2 + xn.z, 0.f);
        o.w = fmaxf(a3 + xn.w, 0.f);
        *(float4*)&ts[tr][c4] = o;
    }

    // ===== phase2: UX2 = ts @ WH + bias (+maskv*v2 on hi), 16x256 =====
    {
        float u0 = 0.f, u1 = 0.f, u2 = 0.f, u3 = 0.f;
        float x0 = 0.f, x1 = 0.f, x2 = 0.f, x3 = 0.f;
        int c8 = tn << 3;
        float4 bva = *(const float4*)(WH + (size_t)tr * 256 + c8);
        float4 bvb = *(const float4*)(WH + (size_t)tr * 256 + c8 + 4);
        for (int k0 = 0; k0 < 128; k0 += 16) {
            __syncthreads();                 // orders ts writes / Bs reuse
            *(float4*)&Bs[tr][c8]     = bva;
            *(float4*)&Bs[tr][c8 + 4] = bvb;
            __syncthreads();
            if (k0 + 16 < 128) {
                bva = *(const float4*)(WH + (size_t)(k0 + 16 + tr) * 256 + c8);
                bvb = *(const float4*)(WH + (size_t)(k0 + 16 + tr) * 256 + c8 + 4);
            }
#pragma unroll
            for (int k = 0; k < 16; ++k) {
                float a = ts[tr][k0 + k];
                float4 b0 = *(const float4*)&Bs[k][c4];          // cols 4tn..   (u half)
                float4 b1 = *(const float4*)&Bs[k][c4 + 128];    // cols 128+4tn (x half)
                u0 = fmaf(a, b0.x, u0); u1 = fmaf(a, b0.y, u1);
                u2 = fmaf(a, b0.z, u2); u3 = fmaf(a, b0.w, u3);
                x0 = fmaf(a, b1.x, x0); x1 = fmaf(a, b1.y, x1);
                x2 = fmaf(a, b1.z, x2); x3 = fmaf(a, b1.w, x3);
            }
        }
        int row = rowBase + tr;
        float rm = maskv[row];
        float4 o0, o1;
        o0.x = u0 + bu2[c4 + 0]; o0.y = u1 + bu2[c4 + 1];
        o0.z = u2 + bu2[c4 + 2]; o0.w = u3 + bu2[c4 + 3];
        o1.x = fmaf(rm, v2[c4 + 0], x0 + bx2[c4 + 0]);
        o1.y = fmaf(rm, v2[c4 + 1], x1 + bx2[c4 + 1]);
        o1.z = fmaf(rm, v2[c4 + 2], x2 + bx2[c4 + 2]);
        o1.w = fmaf(rm, v2[c4 + 3], x3 + bx2[c4 + 3]);
        float* orow = UX2 + (size_t)row * 256;
        *(float4*)(orow + c4)       = o0;
        *(float4*)(orow + 128 + c4) = o1;
    }
    __syncthreads();   // UX2 block-visible (own rows only are read below)

    // ===== msg2 =====
    msg_phase(UX2, w2last);

    // ===== phase4: z2 = relu(xn2 + mhT@M2); proj = z2@pw + pb =====
    {
        float a0 = 0.f, a1 = 0.f, a2 = 0.f, a3 = 0.f;
        float4 bv = *(const float4*)(M2 + (size_t)tr * 128 + c4);
        for (int k0 = 0; k0 < 128; k0 += 16) {
            __syncthreads();                 // orders msg2's mhT writes
            *(float4*)&Bs[tr][c4] = bv;
            __syncthreads();
            if (k0 + 16 < 128)
                bv = *(const float4*)(M2 + (size_t)(k0 + 16 + tr) * 128 + c4);
#pragma unroll
            for (int k = 0; k < 16; ++k) {
                float a = mhT[k0 + k][tr];
                float4 b = *(const float4*)&Bs[k][c4];
                a0 = fmaf(a, b.x, a0); a1 = fmaf(a, b.y, a1);
                a2 = fmaf(a, b.z, a2); a3 = fmaf(a, b.w, a3);
            }
        }
        int row = rowBase + tr;
        float4 xn = *(const float4*)(UX2 + (size_t)row * 256 + 128 + c4);
        float t0 = fmaxf(a0 + xn.x, 0.f);
        float t1 = fmaxf(a1 + xn.y, 0.f);
        float t2 = fmaxf(a2 + xn.z, 0.f);
        float t3 = fmaxf(a3 + xn.w, 0.f);
        float pp0 = fmaf(t3, pw[2*(c4+3)],   fmaf(t2, pw[2*(c4+2)],   fmaf(t1, pw[2*(c4+1)],   t0 * pw[2*c4])));
        float pp1 = fmaf(t3, pw[2*(c4+3)+1], fmaf(t2, pw[2*(c4+2)+1], fmaf(t1, pw[2*(c4+1)+1], t0 * pw[2*c4+1])));
        for (int off = 16; off > 0; off >>= 1) {
            pp0 += __shfl_xor(pp0, off, 64);
            pp1 += __shfl_xor(pp1, off, 64);
        }
        if (tn == 0) {
            proj[2 * row]     = pp0 + pb[0];
            proj[2 * row + 1] = pp1 + pb[1];
        }
    }
}

__global__ void dist_kernel(const float* __restrict__ proj, const int* __restrict__ idxs,
                            float* __restrict__ out, int e) {
    int i = blockIdx.x * blockDim.x + threadIdx.x;
    if (i >= e) return;
    int n = i / KNB;
    int m = idxs[i];
    float2 pn = *(const float2*)(proj + 2 * n);
    float2 pm = *(const float2*)(proj + 2 * m);
    float dx = pn.x - pm.x;
    float dy = pn.y - pm.y;
    out[i] = dx * dx + dy * dy;
}

// ---------------------------------------------------------------------------
extern "C" void kernel_launch(void* const* d_in, const int* in_sizes, int n_in,
                              void* d_out, int out_size, void* d_ws, size_t ws_size,
                              hipStream_t stream) {
    (void)in_sizes; (void)n_in; (void)out_size; (void)ws_size;
    const float* x    = (const float*)d_in[0];
    const float* eatt = (const float*)d_in[1];
    const int*   idxs = (const int*)d_in[2];
    const float* mw1  = (const float*)d_in[3];
    const float* mb1  = (const float*)d_in[4];
    const float* mw2  = (const float*)d_in[5];
    const float* mb2  = (const float*)d_in[6];
    const float* nw1  = (const float*)d_in[7];
    const float* nb1  = (const float*)d_in[8];
    const float* nw2  = (const float*)d_in[9];
    const float* nb2  = (const float*)d_in[10];
    const float* m2w1 = (const float*)d_in[11];
    const float* m2b1 = (const float*)d_in[12];
    const float* m2w2 = (const float*)d_in[13];
    const float* m2b2 = (const float*)d_in[14];
    const float* n2w1 = (const float*)d_in[15];
    const float* n2b1 = (const float*)d_in[16];
    const float* n2w2 = (const float*)d_in[17];
    const float* n2b2 = (const float*)d_in[18];
    float* out = (float*)d_out;

    float* fws   = (float*)d_ws;
    float* UX1   = fws;                   // 10000*256
    float* UX2   = fws + 2560000;         // 10000*256
    float* proj  = fws + 5120000;         // 10000*2
    float* maskv = fws + 5140000;         // 10000
    float* eas   = fws + 5150016;         // 150000
    float* M1    = fws + 5300016;         // 128*128
    float* M2    = fws + 5316400;         // 128*128
    float* WH    = fws + 5332784;         // 128*256
    float* v1    = fws + 5365552;         // 128
    float* v2    = fws + 5365680;         // 128
    float* bu2   = fws + 5365808;         // 128
    float* bx2   = fws + 5365936;         // 128
    int*   cnt   = (int*)(fws + 5366064);
    int*   fillc = cnt + N_NODES;
    int*   eoff  = fillc + N_NODES;
    // Bt aliases UX2: Bt (1.23 MB) is only live scanfold->fillgemm; UX2 is
    // written (fully) and read only inside tail16, after Bt is dead.
    u16*   Bt    = (u16*)(fws + 2560000); // 3*256*800 bf16 bits

    // L1-2: zero cnt, parallel histogram
    hipMemsetAsync(cnt, 0, N_NODES * sizeof(int), stream);
    count_kernel<<<EBLOCKS, 256, 0, stream>>>(idxs, cnt, E_EDGES);

    // L3: prefix-scan (block 0) + weight folds (1..40) + B bf16x3 split (41..56)
    scanfold_kernel<<<57, 256, 0, stream>>>(mw2, mb2, nw1, nb2, nw2,
                                            m2w1, m2b1, m2w2, m2b2, n2w1, n2b1,
                                            M1, M2, WH, v1, v2, bu2, bx2,
                                            cnt, eoff, maskv, fillc, mw1, Bt);

    // L4: MFMA GEMM (1252 blocks, first = LPT) + CSR fill (587 blocks)
    fillgemm_kernel<<<GEMMB + EBLOCKS, 256, 0, stream>>>(
        idxs, eatt, eoff, fillc, eas,
        x, Bt, mb1, nb1, v1, maskv, UX1);

    // L5: tail at 16 rows/block, 625 blocks, 512 threads
    tail16_kernel<<<625, 512, 0, stream>>>(UX1, mw1 + 784 * 128, eas, eoff, cnt, maskv,
                                           M1, WH, bu2, bx2, v2,
                                           m2w1 + 128 * 128, M2,
                                           n2w2, n2b2,
                                           UX2, proj);

    // L6: per-edge squared distances
    dist_kernel<<<EBLOCKS, 256, 0, stream>>>(proj, idxs, out, E_EDGES);
}